// Round 18
// baseline (84.055 us; speedup 1.0000x reference)
//
#include <hip/hip_runtime.h>
#include <hip/hip_fp16.h>
#include <math.h>

#define XD 128
#define YD 128
#define ZD 96
#define NV (XD*YD*ZD)      /* 1572864 voxels per volume */
#define SXX (YD*ZD)        /* x-stride = 12288 */
#define SENT 49152         /* sentinel: > any real d^2 (max 41283) */
#define TW2 114            /* u16 cols: 8 pad | 96 z | 10 pad; 57 dw, 57%32=25 */
#define TDW (TW2/2)        /* 57 dwords per row */
#define TROWS 144          /* rows: 8 pad | 128 y | 8 pad */
#define SCANB 192          /* scan blocks per batch */
#define PROBB 1024         /* prob blocks per batch: 1024*384 = NV/4 exactly */

// -------- block-specialized: scan blocks + softmax blocks, one dispatch ----
__global__ __launch_bounds__(384) void k_scan_prob(const int* __restrict__ gt,
                                                   const float* __restrict__ net,
                                                   unsigned char* __restrict__ out,
                                                   __half2* __restrict__ probs,
                                                   int* __restrict__ flags,
                                                   int batch0) {
    const int bb  = blockIdx.y;
    const int myb = batch0 + bb;
    const int tid = threadIdx.x;

    if (blockIdx.x >= SCANB) {           // ---------------- prob role ----
        const int p = (blockIdx.x - SCANB) * 384 + tid;   // quad index < NV/4
        const int idx = p * 4;
        const float* nb = net + (size_t)myb * 4 * NV;
        float4 v0 = *(const float4*)(nb + idx);
        float4 v1 = *(const float4*)(nb + NV + idx);
        float4 v2 = *(const float4*)(nb + 2 * NV + idx);
        float4 v3 = *(const float4*)(nb + 3 * NV + idx);

        const float a0[4] = {v0.x, v0.y, v0.z, v0.w};
        const float a1[4] = {v1.x, v1.y, v1.z, v1.w};
        const float a2[4] = {v2.x, v2.y, v2.z, v2.w};
        const float a3[4] = {v3.x, v3.y, v3.z, v3.w};
        float p1[4], p2[4], p3[4];
#pragma unroll
        for (int j = 0; j < 4; ++j) {
            float mx = fmaxf(fmaxf(a0[j], a1[j]), fmaxf(a2[j], a3[j]));
            float e0 = __expf(a0[j] - mx);
            float e1 = __expf(a1[j] - mx);
            float e2 = __expf(a2[j] - mx);
            float e3 = __expf(a3[j] - mx);
            float iv = __frcp_rn(e0 + e1 + e2 + e3);
            p1[j] = e1 * iv; p2[j] = e2 * iv; p3[j] = e3 * iv;
        }
        __half2 h10 = __floats2half2_rn(p1[0], p1[1]);
        __half2 h11 = __floats2half2_rn(p1[2], p1[3]);
        __half2 h20 = __floats2half2_rn(p2[0], p2[1]);
        __half2 h21 = __floats2half2_rn(p2[2], p2[3]);
        __half2 h30 = __floats2half2_rn(p3[0], p3[1]);
        __half2 h31 = __floats2half2_rn(p3[2], p3[3]);
        ((__half2*)probs)[(size_t)(myb * 3 + 0) * (NV / 2) + 2 * p]     = h10;
        ((__half2*)probs)[(size_t)(myb * 3 + 0) * (NV / 2) + 2 * p + 1] = h11;
        ((__half2*)probs)[(size_t)(myb * 3 + 1) * (NV / 2) + 2 * p]     = h20;
        ((__half2*)probs)[(size_t)(myb * 3 + 1) * (NV / 2) + 2 * p + 1] = h21;
        ((__half2*)probs)[(size_t)(myb * 3 + 2) * (NV / 2) + 2 * p]     = h30;
        ((__half2*)probs)[(size_t)(myb * 3 + 2) * (NV / 2) + 2 * p + 1] = h31;
        return;
    }

    // ---------------- scan role ----
    const int l   = tid & 63;
    const int w6  = tid >> 6;            // 0..5
    const int lq0 = blockIdx.x * 64;

    __shared__ unsigned char gtile[64 * 132];
    __shared__ int blkbits;
    if (tid == 0) blkbits = 0;

    int mybits = 0;
    const int* gp = gt + (size_t)myb * NV + lq0 + l;
    for (int j = w6; j < XD; j += 6) {
        int g = gp[(size_t)j * SXX];
        mybits |= 1 << g;
        gtile[l * 132 + j] = (unsigned char)g;
    }
#pragma unroll
    for (int off = 32; off; off >>= 1) mybits |= __shfl_xor(mybits, off);
    __syncthreads();
    if ((tid & 63) == 0) atomicOr(&blkbits, mybits);

    unsigned int D[32];
    {   // thread = (slot w6, line l); all in registers
        const unsigned int ci = (unsigned int)((w6 >> 1) + 1);
        const int s = w6 & 1;
        unsigned int G[32];
        const unsigned int* grow = (const unsigned int*)gtile + l * 33;
#pragma unroll
        for (int q = 0; q < 32; ++q) G[q] = grow[q];

        int cnt = 200;
#pragma unroll
        for (int q = 0; q < 32; ++q) {
            unsigned int u = G[q], dv = 0;
#pragma unroll
            for (int b = 0; b < 4; ++b) {
                unsigned int gv = (u >> (8 * b)) & 255u;
                bool zero = s ? (gv == ci) : (gv != ci);
                cnt = zero ? 0 : ((cnt < 200) ? cnt + 1 : 200);
                dv |= (unsigned int)cnt << (8 * b);
            }
            D[q] = dv;
        }
        cnt = 200;
#pragma unroll
        for (int q = 31; q >= 0; --q) {
            unsigned int u = G[q], dv = D[q];
#pragma unroll
            for (int b = 3; b >= 0; --b) {
                unsigned int gv = (u >> (8 * b)) & 255u;
                bool zero = s ? (gv == ci) : (gv != ci);
                cnt = zero ? 0 : ((cnt < 200) ? cnt + 1 : 200);
                unsigned int old = (dv >> (8 * b)) & 255u;
                unsigned int nbv = ((unsigned int)cnt < old) ? (unsigned int)cnt : old;
                dv = (dv & ~(255u << (8 * b))) | (nbv << (8 * b));
            }
            D[q] = dv;
        }
    }
    __syncthreads();                     // blkbits complete
    if (tid == 0) atomicOr(&flags[myb], blkbits);

    // in-wave 4x4 byte transpose (groups of 4 lanes = 4 lines) + store
    {
        const int r = l & 3;
        unsigned char* ob = out + (size_t)(bb * 6 + w6) * NV + lq0 + (l & ~3);
#pragma unroll
        for (int q = 0; q < 32; ++q) {
            unsigned int A = D[q];
            unsigned int Bv = (unsigned int)__shfl_xor((int)A, 1);
            unsigned int t = (r & 1)
                ? __builtin_amdgcn_perm(A, Bv, 0x07030501u)
                : __builtin_amdgcn_perm(A, Bv, 0x02060004u);
            unsigned int Cv = (unsigned int)__shfl_xor((int)t, 2);
            unsigned int y = (r & 2)
                ? __builtin_amdgcn_perm(t, Cv, 0x07060302u)
                : __builtin_amdgcn_perm(t, Cv, 0x01000504u);
            *(unsigned int*)(ob + (size_t)(4 * q + r) * SXX) = y;
        }
    }
}

// ------------- EDT fast path: t<=8 on a 32-float register window -----------
__device__ __forceinline__ bool edt_fast(const float r[32], float m[16]) {
#pragma unroll
    for (int k = 0; k < 16; ++k) m[k] = r[k + 8];
#pragma unroll
    for (int t = 1; t <= 4; ++t) {
        const float t2 = (float)(t * t);
#pragma unroll
        for (int k = 0; k < 16; ++k)
            m[k] = fminf(m[k], fminf(r[k + 8 - t], r[k + 8 + t]) + t2);
    }
    float mm = m[0];
#pragma unroll
    for (int k = 1; k < 16; ++k) mm = fmaxf(mm, m[k]);
    if (__all(mm <= 16.0f)) return true;
#pragma unroll
    for (int t = 5; t <= 8; ++t) {
        const float t2 = (float)(t * t);
#pragma unroll
        for (int k = 0; k < 16; ++k)
            m[k] = fminf(m[k], fminf(r[k + 8 - t], r[k + 8 + t]) + t2);
    }
    mm = m[0];
#pragma unroll
    for (int k = 1; k < 16; ++k) mm = fmaxf(mm, m[k]);
    return __all(mm <= 64.0f) != 0;
}

// ------- EDT slow path (rare): force-inlined so m[] stays in registers -----
template<int STRIDE, int L>
__device__ __forceinline__ void edt_slow(const unsigned short* __restrict__ p0,
                                         int i0, float m[16]) {
    int t = 9;
    bool done = false;
    while (!done && t < L) {
        for (int u = 0; u < 4; ++u, ++t) {
            float t2 = (float)(t * t);
#pragma unroll
            for (int k = 0; k < 16; ++k) {
                int jm = i0 + k - t; if (jm < -8) jm = -8;
                int jp = i0 + k + t; if (jp > L + 7) jp = L + 7;
                m[k] = fminf(m[k], fminf((float)p0[jm * STRIDE],
                                         (float)p0[jp * STRIDE]) + t2);
            }
        }
        float mm = m[0];
#pragma unroll
        for (int k = 1; k < 16; ++k) mm = fmaxf(mm, m[k]);
        done = __all(mm <= (float)((t - 1) * (t - 1))) != 0;
    }
}

// ------------- Y+Z pass: ONE plane per block (short critical path) ---------
// Tile u16 [y][z], all accesses conflict-free. Absent classes early-out.
__global__ __launch_bounds__(768) void k_pass_yz(const unsigned char* __restrict__ in,
                                                 unsigned short* __restrict__ zbuf,
                                                 const int* __restrict__ flags,
                                                 int batch0) {
    const int lv  = blockIdx.y;          // volume slot = bb*6 + 2*c + s
    const int x   = blockIdx.x;
    const int tid = threadIdx.x;
    const int bbp = lv / 6;
    const int cp  = (lv % 6) >> 1;
    if (((flags[batch0 + bbp] >> (cp + 1)) & 1) == 0) return;  // accum skips

    __shared__ unsigned short tile[TROWS * TW2];
    unsigned int* t32 = (unsigned int*)tile;

    for (int i = tid; i < 16 * TDW; i += 768) {
        int r = i / TDW, c = i - r * TDW;
        int row = (r < 8) ? r : 128 + r;
        t32[row * TDW + c] = 0xFFFFFFFFu;
    }
    for (int i = tid; i < 128 * 9; i += 768) {
        int r = i / 9, c = i - r * 9;
        int col = (c < 4) ? c : (48 + c);
        t32[(8 + r) * TDW + col] = 0xFFFFFFFFu;
    }
    {   // stage: u8 d -> u16 d^2; exactly one uint4 (16 z, same y) per thread
        const uint4* ip = (const uint4*)(in + (size_t)lv * NV + (size_t)x * SXX);
        uint4 v = ip[tid];
        int e = tid * 16;
        int y = e / ZD, z = e - y * ZD;
        unsigned int base = (8 + y) * TDW + (8 + z) / 2;
        unsigned int vv[4] = {v.x, v.y, v.z, v.w};
#pragma unroll
        for (int q = 0; q < 4; ++q) {
            unsigned int b0 = vv[q] & 255u, b1 = (vv[q] >> 8) & 255u;
            unsigned int b2 = (vv[q] >> 16) & 255u, b3 = vv[q] >> 24;
            t32[base + 2 * q] = (b0 > 127u ? SENT : b0 * b0) |
                                ((b1 > 127u ? SENT : b1 * b1) << 16);
            t32[base + 2 * q + 1] = (b2 > 127u ? SENT : b2 * b2) |
                                    ((b3 > 127u ? SENT : b3 * b3) << 16);
        }
    }
    __syncthreads();

    float m[16];
    {   // ---- phase Y ----
        const int z0 = tid % 96;
        const int i0 = (tid / 96) * 16;
        float r[32];
#pragma unroll
        for (int w = 0; w < 32; ++w) r[w] = (float)tile[(i0 + w) * TW2 + 8 + z0];
        if (!edt_fast(r, m)) edt_slow<TW2, YD>(&tile[8 * TW2 + 8 + z0], i0, m);
        __syncthreads();
#pragma unroll
        for (int k = 0; k < 16; ++k)
            tile[(8 + i0 + k) * TW2 + 8 + z0] =
                (unsigned short)fminf(m[k], (float)SENT);
        __syncthreads();
    }
    {   // ---- phase Z ----
        const int y0 = tid % 128;
        const int i0 = (tid / 128) * 16;
        float r[32];
        const unsigned int* wp = &t32[(8 + y0) * TDW + i0 / 2];
#pragma unroll
        for (int q = 0; q < 16; ++q) {
            unsigned int u = wp[q];
            r[2 * q] = (float)(u & 0xFFFFu);
            r[2 * q + 1] = (float)(u >> 16);
        }
        if (!edt_fast(r, m)) edt_slow<1, ZD>(&tile[(8 + y0) * TW2 + 8], i0, m);
        // write final d^2 straight to zbuf (contiguous dwords, coalesced)
        unsigned int* op = (unsigned int*)(zbuf + (size_t)lv * NV +
                                           (size_t)x * SXX +
                                           (size_t)y0 * ZD + i0);
#pragma unroll
        for (int q = 0; q < 8; ++q) {
            unsigned int u0 = (unsigned int)fminf(m[2 * q],     (float)SENT);
            unsigned int u1 = (unsigned int)fminf(m[2 * q + 1], (float)SENT);
            op[q] = u0 | (u1 << 16);
        }
    }
}

// ---------------- accum: probs f16 + dp==1 boundary, no gt -----------------
__global__ __launch_bounds__(256) void k_accum(const unsigned short* __restrict__ vols,
                                               const __half2* __restrict__ probs,
                                               const int* __restrict__ flags,
                                               double* __restrict__ partials,
                                               int batch0) {
    const int b = batch0 + blockIdx.y;
    const unsigned short* vb = vols + (size_t)blockIdx.y * 6 * NV;
    const int fbits = flags[b];
    double ls = 0.0;
    for (int p = blockIdx.x * 256 + threadIdx.x; p < NV / 2; p += 1024 * 256) {
        const int idx = p * 2;
        float acc = 0.0f;
#pragma unroll
        for (int ci = 1; ci <= 3; ++ci) {
            if ((fbits >> ci) & 1) {
                ushort2 dp = *(const ushort2*)(vb + (size_t)(2 * ci - 2) * NV + idx);
                ushort2 dn = *(const ushort2*)(vb + (size_t)(2 * ci - 1) * NV + idx);
                float2 pf = __half22float2(
                    probs[(size_t)(b * 3 + ci - 1) * (NV / 2) + p]);
                float phi0 = (dp.x == 1) ? 0.0f
                           : (sqrtf((float)dn.x) - sqrtf((float)dp.x));
                float phi1 = (dp.y == 1) ? 0.0f
                           : (sqrtf((float)dn.y) - sqrtf((float)dp.y));
                acc += pf.x * phi0 + pf.y * phi1;
            }
        }
        ls += (double)acc;
    }
    __shared__ double sd[256];
    sd[threadIdx.x] = ls;
    __syncthreads();
    for (int off = 128; off > 0; off >>= 1) {
        if (threadIdx.x < off) sd[threadIdx.x] += sd[threadIdx.x + off];
        __syncthreads();
    }
    if (threadIdx.x == 0) partials[(size_t)b * 1024 + blockIdx.x] = sd[0];
}

// -------------------------------------------------------------- reduce ----
__global__ void k_reduce(const double* __restrict__ partials, int n,
                         float* __restrict__ out) {
    __shared__ double sd[256];
    double ls = 0.0;
    for (int i = threadIdx.x; i < n; i += 256) ls += partials[i];
    sd[threadIdx.x] = ls;
    __syncthreads();
    for (int off = 128; off > 0; off >>= 1) {
        if (threadIdx.x < off) sd[threadIdx.x] += sd[threadIdx.x + off];
        __syncthreads();
    }
    if (threadIdx.x == 0) out[0] = (float)(sd[0] / 9437184.0);
}

// ---------------------------------------------------------------- launch ----
extern "C" void kernel_launch(void* const* d_in, const int* in_sizes, int n_in,
                              void* d_out, int out_size, void* d_ws, size_t ws_size,
                              hipStream_t stream) {
    const float* net = (const float*)d_in[0];
    const int*   gt  = (const int*)d_in[1];
    float* out = (float*)d_out;
    char* ws = (char*)d_ws;

    const size_t xbufB1 = (size_t)6 * NV;                          // u8, 9.4 MB
    const size_t zbufB1 = (size_t)6 * NV * sizeof(unsigned short); // u16, 18.9 MB
    const size_t probsB = (size_t)2 * 3 * NV * 2;                  // f16, 18.9 MB
    const size_t tail   = (size_t)2048 * sizeof(double) + 64;

    const int nb = (ws_size >= 2 * (xbufB1 + zbufB1) + probsB + tail) ? 2 : 1;

    unsigned char*  xbuf = (unsigned char*)ws;
    unsigned short* zbuf = (unsigned short*)(ws + (size_t)nb * xbufB1);
    __half2*       probs = (__half2*)(ws + (size_t)nb * (xbufB1 + zbufB1));
    double*     partials = (double*)((char*)probs + probsB);
    int*           flags = (int*)((char*)partials + 2048 * sizeof(double));

    hipMemsetAsync(flags, 0, 8 * sizeof(int), stream);

    for (int b0 = 0; b0 < 2; b0 += nb) {
        hipLaunchKernelGGL(k_scan_prob, dim3(SCANB + PROBB, nb), dim3(384), 0,
                           stream, gt, net, xbuf, probs, flags, b0);
        hipLaunchKernelGGL(k_pass_yz, dim3(XD, 6 * nb), dim3(768), 0, stream,
                           xbuf, zbuf, flags, b0);
        hipLaunchKernelGGL(k_accum, dim3(1024, nb), dim3(256), 0, stream,
                           zbuf, probs, flags, partials, b0);
    }
    hipLaunchKernelGGL(k_reduce, dim3(1), dim3(256), 0, stream, partials,
                       2048, out);
}

// Round 19
// 79.682 us; speedup vs baseline: 1.0549x; 1.0549x over previous
//
#include <hip/hip_runtime.h>
#include <hip/hip_fp16.h>
#include <math.h>

#define XD 128
#define YD 128
#define ZD 96
#define NV (XD*YD*ZD)      /* 1572864 voxels per volume */
#define SXX (YD*ZD)        /* x-stride = 12288 */
#define SENT 49152         /* sentinel: > any real d^2 (max 41283) */
#define TW2 114            /* u16 cols: 8 pad | 96 z | 10 pad; 57 dw, 57%32=25 */
#define TDW (TW2/2)        /* 57 dwords per row */
#define TROWS 144          /* rows: 8 pad | 128 y | 8 pad */
#define SCANB 192          /* scan blocks per batch */
#define PROBB 1024         /* prob blocks per batch: 1024*384 = NV/4 exactly */

// -------- block-specialized: scan blocks + softmax blocks, one dispatch ----
__global__ __launch_bounds__(384) void k_scan_prob(const int* __restrict__ gt,
                                                   const float* __restrict__ net,
                                                   unsigned char* __restrict__ out,
                                                   __half2* __restrict__ probs,
                                                   int* __restrict__ flags,
                                                   int batch0) {
    const int bb  = blockIdx.y;
    const int myb = batch0 + bb;
    const int tid = threadIdx.x;

    if (blockIdx.x >= SCANB) {           // ---------------- prob role ----
        const int p = (blockIdx.x - SCANB) * 384 + tid;   // quad index < NV/4
        const int idx = p * 4;
        const float* nb = net + (size_t)myb * 4 * NV;
        float4 v0 = *(const float4*)(nb + idx);
        float4 v1 = *(const float4*)(nb + NV + idx);
        float4 v2 = *(const float4*)(nb + 2 * NV + idx);
        float4 v3 = *(const float4*)(nb + 3 * NV + idx);

        const float a0[4] = {v0.x, v0.y, v0.z, v0.w};
        const float a1[4] = {v1.x, v1.y, v1.z, v1.w};
        const float a2[4] = {v2.x, v2.y, v2.z, v2.w};
        const float a3[4] = {v3.x, v3.y, v3.z, v3.w};
        float p1[4], p2[4], p3[4];
#pragma unroll
        for (int j = 0; j < 4; ++j) {
            float mx = fmaxf(fmaxf(a0[j], a1[j]), fmaxf(a2[j], a3[j]));
            float e0 = __expf(a0[j] - mx);
            float e1 = __expf(a1[j] - mx);
            float e2 = __expf(a2[j] - mx);
            float e3 = __expf(a3[j] - mx);
            float iv = __frcp_rn(e0 + e1 + e2 + e3);
            p1[j] = e1 * iv; p2[j] = e2 * iv; p3[j] = e3 * iv;
        }
        __half2 h10 = __floats2half2_rn(p1[0], p1[1]);
        __half2 h11 = __floats2half2_rn(p1[2], p1[3]);
        __half2 h20 = __floats2half2_rn(p2[0], p2[1]);
        __half2 h21 = __floats2half2_rn(p2[2], p2[3]);
        __half2 h30 = __floats2half2_rn(p3[0], p3[1]);
        __half2 h31 = __floats2half2_rn(p3[2], p3[3]);
        ((__half2*)probs)[(size_t)(myb * 3 + 0) * (NV / 2) + 2 * p]     = h10;
        ((__half2*)probs)[(size_t)(myb * 3 + 0) * (NV / 2) + 2 * p + 1] = h11;
        ((__half2*)probs)[(size_t)(myb * 3 + 1) * (NV / 2) + 2 * p]     = h20;
        ((__half2*)probs)[(size_t)(myb * 3 + 1) * (NV / 2) + 2 * p + 1] = h21;
        ((__half2*)probs)[(size_t)(myb * 3 + 2) * (NV / 2) + 2 * p]     = h30;
        ((__half2*)probs)[(size_t)(myb * 3 + 2) * (NV / 2) + 2 * p + 1] = h31;
        return;
    }

    // ---------------- scan role ----
    const int l   = tid & 63;
    const int w6  = tid >> 6;            // 0..5
    const int lq0 = blockIdx.x * 64;

    __shared__ unsigned char gtile[64 * 132];
    __shared__ int blkbits;
    if (tid == 0) blkbits = 0;

    int mybits = 0;
    const int* gp = gt + (size_t)myb * NV + lq0 + l;
    for (int j = w6; j < XD; j += 6) {
        int g = gp[(size_t)j * SXX];
        mybits |= 1 << g;
        gtile[l * 132 + j] = (unsigned char)g;
    }
#pragma unroll
    for (int off = 32; off; off >>= 1) mybits |= __shfl_xor(mybits, off);
    __syncthreads();
    if ((tid & 63) == 0) atomicOr(&blkbits, mybits);

    unsigned int D[32];
    {   // thread = (slot w6, line l); all in registers
        const unsigned int ci = (unsigned int)((w6 >> 1) + 1);
        const int s = w6 & 1;
        unsigned int G[32];
        const unsigned int* grow = (const unsigned int*)gtile + l * 33;
#pragma unroll
        for (int q = 0; q < 32; ++q) G[q] = grow[q];

        int cnt = 200;
#pragma unroll
        for (int q = 0; q < 32; ++q) {
            unsigned int u = G[q], dv = 0;
#pragma unroll
            for (int b = 0; b < 4; ++b) {
                unsigned int gv = (u >> (8 * b)) & 255u;
                bool zero = s ? (gv == ci) : (gv != ci);
                cnt = zero ? 0 : ((cnt < 200) ? cnt + 1 : 200);
                dv |= (unsigned int)cnt << (8 * b);
            }
            D[q] = dv;
        }
        cnt = 200;
#pragma unroll
        for (int q = 31; q >= 0; --q) {
            unsigned int u = G[q], dv = D[q];
#pragma unroll
            for (int b = 3; b >= 0; --b) {
                unsigned int gv = (u >> (8 * b)) & 255u;
                bool zero = s ? (gv == ci) : (gv != ci);
                cnt = zero ? 0 : ((cnt < 200) ? cnt + 1 : 200);
                unsigned int old = (dv >> (8 * b)) & 255u;
                unsigned int nbv = ((unsigned int)cnt < old) ? (unsigned int)cnt : old;
                dv = (dv & ~(255u << (8 * b))) | (nbv << (8 * b));
            }
            D[q] = dv;
        }
    }
    __syncthreads();                     // blkbits complete
    if (tid == 0) atomicOr(&flags[myb], blkbits);

    // in-wave 4x4 byte transpose (groups of 4 lanes = 4 lines) + store
    {
        const int r = l & 3;
        unsigned char* ob = out + (size_t)(bb * 6 + w6) * NV + lq0 + (l & ~3);
#pragma unroll
        for (int q = 0; q < 32; ++q) {
            unsigned int A = D[q];
            unsigned int Bv = (unsigned int)__shfl_xor((int)A, 1);
            unsigned int t = (r & 1)
                ? __builtin_amdgcn_perm(A, Bv, 0x07030501u)
                : __builtin_amdgcn_perm(A, Bv, 0x02060004u);
            unsigned int Cv = (unsigned int)__shfl_xor((int)t, 2);
            unsigned int y = (r & 2)
                ? __builtin_amdgcn_perm(t, Cv, 0x07060302u)
                : __builtin_amdgcn_perm(t, Cv, 0x01000504u);
            *(unsigned int*)(ob + (size_t)(4 * q + r) * SXX) = y;
        }
    }
}

// ------------- EDT fast path: t<=8 on a 32-float register window -----------
__device__ __forceinline__ bool edt_fast(const float r[32], float m[16]) {
#pragma unroll
    for (int k = 0; k < 16; ++k) m[k] = r[k + 8];
#pragma unroll
    for (int t = 1; t <= 4; ++t) {
        const float t2 = (float)(t * t);
#pragma unroll
        for (int k = 0; k < 16; ++k)
            m[k] = fminf(m[k], fminf(r[k + 8 - t], r[k + 8 + t]) + t2);
    }
    float mm = m[0];
#pragma unroll
    for (int k = 1; k < 16; ++k) mm = fmaxf(mm, m[k]);
    if (__all(mm <= 16.0f)) return true;
#pragma unroll
    for (int t = 5; t <= 8; ++t) {
        const float t2 = (float)(t * t);
#pragma unroll
        for (int k = 0; k < 16; ++k)
            m[k] = fminf(m[k], fminf(r[k + 8 - t], r[k + 8 + t]) + t2);
    }
    mm = m[0];
#pragma unroll
    for (int k = 1; k < 16; ++k) mm = fmaxf(mm, m[k]);
    return __all(mm <= 64.0f) != 0;
}

// ------- EDT slow path (rare): force-inlined so m[] stays in registers -----
template<int STRIDE, int L>
__device__ __forceinline__ void edt_slow(const unsigned short* __restrict__ p0,
                                         int i0, float m[16]) {
    int t = 9;
    bool done = false;
    while (!done && t < L) {
        for (int u = 0; u < 4; ++u, ++t) {
            float t2 = (float)(t * t);
#pragma unroll
            for (int k = 0; k < 16; ++k) {
                int jm = i0 + k - t; if (jm < -8) jm = -8;
                int jp = i0 + k + t; if (jp > L + 7) jp = L + 7;
                m[k] = fminf(m[k], fminf((float)p0[jm * STRIDE],
                                         (float)p0[jp * STRIDE]) + t2);
            }
        }
        float mm = m[0];
#pragma unroll
        for (int k = 1; k < 16; ++k) mm = fmaxf(mm, m[k]);
        done = __all(mm <= (float)((t - 1) * (t - 1))) != 0;
    }
}

// ---- fused Y+Z EDT + dot: ONE (x, class, SIGN, batch) plane per block -----
// Exact decoupling: p*phi = p*sqrt(dn^2) - p*sqrt(dp^2) + p*[dp^2==1]
// (at dp^2==1 the voxel is foreground so dn^2==0; check: 0 = p*0 - p*1 + p).
// s==0 (pos) blocks accumulate p*([dp^2==1] - sqrt(dp^2)); s==1 (neg) blocks
// accumulate p*sqrt(dn^2). One EDT per block: half the serial chain of the
// old 2-plane fusion, no zbuf, no accum kernel.
__global__ __launch_bounds__(768) void k_edt_dot(const unsigned char* __restrict__ in,
                                                 const __half2* __restrict__ probs,
                                                 const int* __restrict__ flags,
                                                 double* __restrict__ partials,
                                                 int batch0) {
    const int x    = blockIdx.x;
    const int lv   = blockIdx.y;         // local slot: bbl*6 + 2*c + s
    const int bbl  = lv / 6;
    const int slot = lv % 6;
    const int c    = slot >> 1;
    const int s    = slot & 1;
    const int b    = batch0 + bbl;
    const int tid  = threadIdx.x;
    const int pidx = (b * 6 + slot) * XD + x;

    __shared__ unsigned short tile[TROWS * TW2];
    __shared__ double sd[768];
    unsigned int* t32 = (unsigned int*)tile;

    if (((flags[b] >> (c + 1)) & 1) == 0) {
        if (tid == 0) partials[pidx] = 0.0;
        return;
    }

    for (int i = tid; i < 16 * TDW; i += 768) {
        int r = i / TDW, cc = i - r * TDW;
        int row = (r < 8) ? r : 128 + r;
        t32[row * TDW + cc] = 0xFFFFFFFFu;
    }
    for (int i = tid; i < 128 * 9; i += 768) {
        int r = i / 9, cc = i - r * 9;
        int col = (cc < 4) ? cc : (48 + cc);
        t32[(8 + r) * TDW + col] = 0xFFFFFFFFu;
    }
    {   // stage: u8 d -> u16 d^2; exactly one uint4 (16 z, same y) per thread
        const uint4* ip = (const uint4*)(in + (size_t)lv * NV + (size_t)x * SXX);
        uint4 v = ip[tid];
        int e = tid * 16;
        int y = e / ZD, z = e - y * ZD;
        unsigned int base = (8 + y) * TDW + (8 + z) / 2;
        unsigned int vv[4] = {v.x, v.y, v.z, v.w};
#pragma unroll
        for (int q = 0; q < 4; ++q) {
            unsigned int b0 = vv[q] & 255u, b1 = (vv[q] >> 8) & 255u;
            unsigned int b2 = (vv[q] >> 16) & 255u, b3 = vv[q] >> 24;
            t32[base + 2 * q] = (b0 > 127u ? SENT : b0 * b0) |
                                ((b1 > 127u ? SENT : b1 * b1) << 16);
            t32[base + 2 * q + 1] = (b2 > 127u ? SENT : b2 * b2) |
                                    ((b3 > 127u ? SENT : b3 * b3) << 16);
        }
    }
    __syncthreads();

    float m[16];
    {   // ---- phase Y (lanes vary z: conflict-free) ----
        const int z0 = tid % 96;
        const int i0 = (tid / 96) * 16;
        float r[32];
#pragma unroll
        for (int w = 0; w < 32; ++w) r[w] = (float)tile[(i0 + w) * TW2 + 8 + z0];
        if (!edt_fast(r, m)) edt_slow<TW2, YD>(&tile[8 * TW2 + 8 + z0], i0, m);
        __syncthreads();                 // all window reads done
#pragma unroll
        for (int k = 0; k < 16; ++k)
            tile[(8 + i0 + k) * TW2 + 8 + z0] =
                (unsigned short)fminf(m[k], (float)SENT);
        __syncthreads();
    }
    const int y0 = tid % 128;
    const int i0 = (tid / 128) * 16;
    {   // ---- phase Z (rows contiguous, stride-57 coprime) ----
        float r[32];
        const unsigned int* wp = &t32[(8 + y0) * TDW + i0 / 2];
#pragma unroll
        for (int q = 0; q < 16; ++q) {
            unsigned int u = wp[q];
            r[2 * q] = (float)(u & 0xFFFFu);
            r[2 * q + 1] = (float)(u >> 16);
        }
        if (!edt_fast(r, m)) edt_slow<1, ZD>(&tile[(8 + y0) * TW2 + 8], i0, m);
    }

    // ---- dot with probs (own 16 voxels, contiguous in z) ----
    float a = 0.0f;
    {
        const __half2* pv = probs + (size_t)(b * 3 + c) * (NV / 2) +
                            ((size_t)x * SXX + (size_t)y0 * ZD + i0) / 2;
        if (s == 0) {                    // pos: p*([d==1] - sqrt(d))
#pragma unroll
            for (int q = 0; q < 8; ++q) {
                float2 pf = __half22float2(pv[q]);
                float d0 = fminf(m[2 * q],     (float)SENT);
                float d1 = fminf(m[2 * q + 1], (float)SENT);
                float t0 = ((d0 == 1.0f) ? 1.0f : 0.0f) - sqrtf(d0);
                float t1 = ((d1 == 1.0f) ? 1.0f : 0.0f) - sqrtf(d1);
                a += pf.x * t0 + pf.y * t1;
            }
        } else {                         // neg: p*sqrt(d)
#pragma unroll
            for (int q = 0; q < 8; ++q) {
                float2 pf = __half22float2(pv[q]);
                float d0 = fminf(m[2 * q],     (float)SENT);
                float d1 = fminf(m[2 * q + 1], (float)SENT);
                a += pf.x * sqrtf(d0) + pf.y * sqrtf(d1);
            }
        }
    }
    sd[tid] = (double)a;
    __syncthreads();
    for (int off = 512; off; off >>= 1) {
        if (tid < off && tid + off < 768) sd[tid] += sd[tid + off];
        __syncthreads();
    }
    if (tid == 0) partials[pidx] = sd[0];
}

// -------------------------------------------------------------- reduce ----
__global__ void k_reduce(const double* __restrict__ partials, int n,
                         float* __restrict__ out) {
    __shared__ double sd[256];
    double ls = 0.0;
    for (int i = threadIdx.x; i < n; i += 256) ls += partials[i];
    sd[threadIdx.x] = ls;
    __syncthreads();
    for (int off = 128; off > 0; off >>= 1) {
        if (threadIdx.x < off) sd[threadIdx.x] += sd[threadIdx.x + off];
        __syncthreads();
    }
    if (threadIdx.x == 0) out[0] = (float)(sd[0] / 9437184.0);
}

// ---------------------------------------------------------------- launch ----
extern "C" void kernel_launch(void* const* d_in, const int* in_sizes, int n_in,
                              void* d_out, int out_size, void* d_ws, size_t ws_size,
                              hipStream_t stream) {
    const float* net = (const float*)d_in[0];
    const int*   gt  = (const int*)d_in[1];
    float* out = (float*)d_out;
    char* ws = (char*)d_ws;

    const size_t xbufB1 = (size_t)6 * NV;               // u8 per batch, 9.4 MB
    const size_t probsB = (size_t)2 * 3 * NV * 2;       // f16, both batches
    const size_t tail   = (size_t)1536 * sizeof(double) + 64;

    const int nb = (ws_size >= 2 * xbufB1 + probsB + tail) ? 2 : 1;

    unsigned char* xbuf  = (unsigned char*)ws;
    __half2*       probs = (__half2*)(ws + (size_t)nb * xbufB1);
    double*     partials = (double*)((char*)probs + probsB);
    int*           flags = (int*)((char*)partials + 1536 * sizeof(double));

    hipMemsetAsync(flags, 0, 8 * sizeof(int), stream);

    for (int b0 = 0; b0 < 2; b0 += nb) {
        hipLaunchKernelGGL(k_scan_prob, dim3(SCANB + PROBB, nb), dim3(384), 0,
                           stream, gt, net, xbuf, probs, flags, b0);
        hipLaunchKernelGGL(k_edt_dot, dim3(XD, 6 * nb), dim3(768), 0, stream,
                           xbuf, probs, flags, partials, b0);
    }
    hipLaunchKernelGGL(k_reduce, dim3(1), dim3(256), 0, stream, partials,
                       1536, out);
}

// Round 20
// 69.987 us; speedup vs baseline: 1.2010x; 1.1385x over previous
//
#include <hip/hip_runtime.h>
#include <hip/hip_fp16.h>
#include <math.h>

#define XD 128
#define YD 128
#define ZD 96
#define NV (XD*YD*ZD)      /* 1572864 voxels per volume */
#define SXX (YD*ZD)        /* x-stride = 12288 */
#define SENT 49152         /* sentinel: > any real d^2 (max 41283) */
#define SENTP 0xC000C000u  /* packed pair of SENT */
#define TW2 114            /* u16 cols: 8 pad | 96 z | 10 pad; 57 dw */
#define TDW (TW2/2)        /* 57 dwords per row (57%32=25, coprime) */
#define TROWS 144          /* rows: 8 pad | 128 y | 8 pad */
#define SCANB 192          /* scan blocks per batch */
#define PROBB 1024         /* prob blocks per batch: 1024*384 = NV/4 */

// -------- block-specialized: scan blocks + softmax blocks, one dispatch ----
__global__ __launch_bounds__(384) void k_scan_prob(const int* __restrict__ gt,
                                                   const float* __restrict__ net,
                                                   unsigned char* __restrict__ out,
                                                   __half2* __restrict__ probs,
                                                   int* __restrict__ flags,
                                                   int batch0) {
    const int bb  = blockIdx.y;
    const int myb = batch0 + bb;
    const int tid = threadIdx.x;

    if (blockIdx.x >= SCANB) {           // ---------------- prob role ----
        const int p = (blockIdx.x - SCANB) * 384 + tid;   // quad index < NV/4
        const int idx = p * 4;
        const float* nb = net + (size_t)myb * 4 * NV;
        float4 v0 = *(const float4*)(nb + idx);
        float4 v1 = *(const float4*)(nb + NV + idx);
        float4 v2 = *(const float4*)(nb + 2 * NV + idx);
        float4 v3 = *(const float4*)(nb + 3 * NV + idx);

        const float a0[4] = {v0.x, v0.y, v0.z, v0.w};
        const float a1[4] = {v1.x, v1.y, v1.z, v1.w};
        const float a2[4] = {v2.x, v2.y, v2.z, v2.w};
        const float a3[4] = {v3.x, v3.y, v3.z, v3.w};
        float p1[4], p2[4], p3[4];
#pragma unroll
        for (int j = 0; j < 4; ++j) {
            float mx = fmaxf(fmaxf(a0[j], a1[j]), fmaxf(a2[j], a3[j]));
            float e0 = __expf(a0[j] - mx);
            float e1 = __expf(a1[j] - mx);
            float e2 = __expf(a2[j] - mx);
            float e3 = __expf(a3[j] - mx);
            float iv = __frcp_rn(e0 + e1 + e2 + e3);
            p1[j] = e1 * iv; p2[j] = e2 * iv; p3[j] = e3 * iv;
        }
        probs[(size_t)(myb * 3 + 0) * (NV / 2) + 2 * p]     = __floats2half2_rn(p1[0], p1[1]);
        probs[(size_t)(myb * 3 + 0) * (NV / 2) + 2 * p + 1] = __floats2half2_rn(p1[2], p1[3]);
        probs[(size_t)(myb * 3 + 1) * (NV / 2) + 2 * p]     = __floats2half2_rn(p2[0], p2[1]);
        probs[(size_t)(myb * 3 + 1) * (NV / 2) + 2 * p + 1] = __floats2half2_rn(p2[2], p2[3]);
        probs[(size_t)(myb * 3 + 2) * (NV / 2) + 2 * p]     = __floats2half2_rn(p3[0], p3[1]);
        probs[(size_t)(myb * 3 + 2) * (NV / 2) + 2 * p + 1] = __floats2half2_rn(p3[2], p3[3]);
        return;
    }

    // ---------------- scan role ----
    const int l   = tid & 63;
    const int w6  = tid >> 6;            // 0..5
    const int lq0 = blockIdx.x * 64;

    __shared__ unsigned char gtile[64 * 132];
    __shared__ int blkbits;
    if (tid == 0) blkbits = 0;

    int mybits = 0;
    const int* gp = gt + (size_t)myb * NV + lq0 + l;
    for (int j = w6; j < XD; j += 6) {
        int g = gp[(size_t)j * SXX];
        mybits |= 1 << g;
        gtile[l * 132 + j] = (unsigned char)g;
    }
#pragma unroll
    for (int off = 32; off; off >>= 1) mybits |= __shfl_xor(mybits, off);
    __syncthreads();
    if ((tid & 63) == 0) atomicOr(&blkbits, mybits);

    unsigned int D[32];
    {
        const unsigned int ci = (unsigned int)((w6 >> 1) + 1);
        const int s = w6 & 1;
        unsigned int G[32];
        const unsigned int* grow = (const unsigned int*)gtile + l * 33;
#pragma unroll
        for (int q = 0; q < 32; ++q) G[q] = grow[q];

        int cnt = 200;
#pragma unroll
        for (int q = 0; q < 32; ++q) {
            unsigned int u = G[q], dv = 0;
#pragma unroll
            for (int b = 0; b < 4; ++b) {
                unsigned int gv = (u >> (8 * b)) & 255u;
                bool zero = s ? (gv == ci) : (gv != ci);
                cnt = zero ? 0 : ((cnt < 200) ? cnt + 1 : 200);
                dv |= (unsigned int)cnt << (8 * b);
            }
            D[q] = dv;
        }
        cnt = 200;
#pragma unroll
        for (int q = 31; q >= 0; --q) {
            unsigned int u = G[q], dv = D[q];
#pragma unroll
            for (int b = 3; b >= 0; --b) {
                unsigned int gv = (u >> (8 * b)) & 255u;
                bool zero = s ? (gv == ci) : (gv != ci);
                cnt = zero ? 0 : ((cnt < 200) ? cnt + 1 : 200);
                unsigned int old = (dv >> (8 * b)) & 255u;
                unsigned int nbv = ((unsigned int)cnt < old) ? (unsigned int)cnt : old;
                dv = (dv & ~(255u << (8 * b))) | (nbv << (8 * b));
            }
            D[q] = dv;
        }
    }
    __syncthreads();
    if (tid == 0) atomicOr(&flags[myb], blkbits);

    {   // in-wave 4x4 byte transpose + store
        const int r = l & 3;
        unsigned char* ob = out + (size_t)(bb * 6 + w6) * NV + lq0 + (l & ~3);
#pragma unroll
        for (int q = 0; q < 32; ++q) {
            unsigned int A = D[q];
            unsigned int Bv = (unsigned int)__shfl_xor((int)A, 1);
            unsigned int t = (r & 1)
                ? __builtin_amdgcn_perm(A, Bv, 0x07030501u)
                : __builtin_amdgcn_perm(A, Bv, 0x02060004u);
            unsigned int Cv = (unsigned int)__shfl_xor((int)t, 2);
            unsigned int y = (r & 2)
                ? __builtin_amdgcn_perm(t, Cv, 0x07060302u)
                : __builtin_amdgcn_perm(t, Cv, 0x01000504u);
            *(unsigned int*)(ob + (size_t)(4 * q + r) * SXX) = y;
        }
    }
}

// -------------------- packed-u16 primitives (VOP3P) ------------------------
__device__ __forceinline__ unsigned int pk_min(unsigned int a, unsigned int b) {
    unsigned int d;
    asm("v_pk_min_u16 %0, %1, %2" : "=v"(d) : "v"(a), "v"(b));
    return d;
}
__device__ __forceinline__ unsigned int pk_max(unsigned int a, unsigned int b) {
    unsigned int d;
    asm("v_pk_max_u16 %0, %1, %2" : "=v"(d) : "v"(a), "v"(b));
    return d;
}
__device__ __forceinline__ unsigned int pk_add(unsigned int a, unsigned int b) {
    unsigned int d;
    asm("v_pk_add_u16 %0, %1, %2" : "=v"(d) : "v"(a), "v"(b));
    return d;
}
// all values <= 49152+127^2 = 65281 < 2^16: no overflow anywhere.

__device__ __forceinline__ bool pk_done(const unsigned int m[8], int thr) {
    unsigned int mx = m[0];
#pragma unroll
    for (int k = 1; k < 8; ++k) mx = pk_max(mx, m[k]);
    int a = (int)(mx & 0xFFFFu), bq = (int)(mx >> 16);
    int amax = a > bq ? a : bq;
    return __all(amax <= thr) != 0;
}

// ------- scalar slow paths (rare; force-inlined, register-resident) --------
template<int STRIDE, int L>
__device__ __forceinline__ void edt_slow8(const unsigned short* __restrict__ p0,
                                          int i0, float m[8]) {
    int t = 9;
    bool done = false;
    while (!done && t < L) {
        for (int u = 0; u < 4; ++u, ++t) {
            float t2 = (float)(t * t);
#pragma unroll
            for (int k = 0; k < 8; ++k) {
                int jm = i0 + k - t; if (jm < -8) jm = -8;
                int jp = i0 + k + t; if (jp > L + 7) jp = L + 7;
                m[k] = fminf(m[k], fminf((float)p0[jm * STRIDE],
                                         (float)p0[jp * STRIDE]) + t2);
            }
        }
        float mm = m[0];
#pragma unroll
        for (int k = 1; k < 8; ++k) mm = fmaxf(mm, m[k]);
        done = __all(mm <= (float)((t - 1) * (t - 1))) != 0;
    }
}
template<int STRIDE, int L>
__device__ __forceinline__ void edt_slow16(const unsigned short* __restrict__ p0,
                                           int i0, float m[16]) {
    int t = 9;
    bool done = false;
    while (!done && t < L) {
        for (int u = 0; u < 4; ++u, ++t) {
            float t2 = (float)(t * t);
#pragma unroll
            for (int k = 0; k < 16; ++k) {
                int jm = i0 + k - t; if (jm < -8) jm = -8;
                int jp = i0 + k + t; if (jp > L + 7) jp = L + 7;
                m[k] = fminf(m[k], fminf((float)p0[jm * STRIDE],
                                         (float)p0[jp * STRIDE]) + t2);
            }
        }
        float mm = m[0];
#pragma unroll
        for (int k = 1; k < 16; ++k) mm = fmaxf(mm, m[k]);
        done = __all(mm <= (float)((t - 1) * (t - 1))) != 0;
    }
}

// ---- phase Y packed EDT: 8 y-outputs x one z-pair per thread --------------
// zp = z-pair (0..47), i0 = first y output. Shifts move along y (rows), so
// packed pairs NEVER misalign. 3 pk-ops per (t,k) for 2 voxels.
__device__ __forceinline__ void edtY_pk(unsigned int* __restrict__ t32,
                                        unsigned short* __restrict__ tile,
                                        int zp, int i0, unsigned int m[8]) {
    unsigned int w[24];
    unsigned int* colp = t32 + 4 + zp;
#pragma unroll
    for (int q = 0; q < 24; ++q) w[q] = colp[(i0 + q) * TDW];
#pragma unroll
    for (int k = 0; k < 8; ++k) m[k] = w[k + 8];
#pragma unroll
    for (int t = 1; t <= 4; ++t) {
        const unsigned int t2p = (unsigned int)(t * t) * 0x00010001u;
#pragma unroll
        for (int k = 0; k < 8; ++k)
            m[k] = pk_min(m[k], pk_add(pk_min(w[k + 8 - t], w[k + 8 + t]), t2p));
    }
    bool done = pk_done(m, 16);
    if (!done) {
#pragma unroll
        for (int t = 5; t <= 8; ++t) {
            const unsigned int t2p = (unsigned int)(t * t) * 0x00010001u;
#pragma unroll
            for (int k = 0; k < 8; ++k)
                m[k] = pk_min(m[k], pk_add(pk_min(w[k + 8 - t], w[k + 8 + t]), t2p));
        }
        done = pk_done(m, 64);
    }
    if (!done) {                         // rare scalar fallback, per z half
#pragma unroll
        for (int h = 0; h < 2; ++h) {
            float fm[8];
#pragma unroll
            for (int k = 0; k < 8; ++k)
                fm[k] = (float)(h ? (m[k] >> 16) : (m[k] & 0xFFFFu));
            edt_slow8<TW2, YD>(&tile[8 * TW2 + 8 + 2 * zp + h], i0, fm);
#pragma unroll
            for (int k = 0; k < 8; ++k) {
                unsigned int v = (unsigned int)fm[k];
                m[k] = h ? ((m[k] & 0x0000FFFFu) | (v << 16))
                         : ((m[k] & 0xFFFF0000u) | v);
            }
        }
    }
#pragma unroll
    for (int k = 0; k < 8; ++k) m[k] = pk_min(m[k], SENTP);
}

// ---- phase Z packed EDT: 8 z-pair outputs x one y per thread --------------
// Shifts move along z (the packed axis): odd t uses v_alignbit to form the
// misaligned pair. Result left UNCLAMPED in m (caller clamps).
__device__ __forceinline__ void edtZ_pk(const unsigned int* __restrict__ t32,
                                        const unsigned short* __restrict__ tile,
                                        int y0, int ch, unsigned int m[8]) {
    unsigned int w[16];
    const unsigned int* rowp = t32 + (size_t)(8 + y0) * TDW;
#pragma unroll
    for (int q = 0; q < 16; ++q) w[q] = rowp[8 * ch + q];
#pragma unroll
    for (int k = 0; k < 8; ++k) m[k] = w[k + 4];
#pragma unroll
    for (int t = 1; t <= 4; ++t) {
        const unsigned int t2p = (unsigned int)(t * t) * 0x00010001u;
#pragma unroll
        for (int k = 0; k < 8; ++k) {
            unsigned int lo, hi;
            if (t & 1) {
                lo = __builtin_amdgcn_alignbit(w[k + 4 - (t - 1) / 2],
                                               w[k + 4 - (t + 1) / 2], 16);
                hi = __builtin_amdgcn_alignbit(w[k + 4 + (t + 1) / 2],
                                               w[k + 4 + (t - 1) / 2], 16);
            } else {
                lo = w[k + 4 - t / 2]; hi = w[k + 4 + t / 2];
            }
            m[k] = pk_min(m[k], pk_add(pk_min(lo, hi), t2p));
        }
    }
    bool done = pk_done(m, 16);
    if (!done) {
#pragma unroll
        for (int t = 5; t <= 8; ++t) {
            const unsigned int t2p = (unsigned int)(t * t) * 0x00010001u;
#pragma unroll
            for (int k = 0; k < 8; ++k) {
                unsigned int lo, hi;
                if (t & 1) {
                    lo = __builtin_amdgcn_alignbit(w[k + 4 - (t - 1) / 2],
                                                   w[k + 4 - (t + 1) / 2], 16);
                    hi = __builtin_amdgcn_alignbit(w[k + 4 + (t + 1) / 2],
                                                   w[k + 4 + (t - 1) / 2], 16);
                } else {
                    lo = w[k + 4 - t / 2]; hi = w[k + 4 + t / 2];
                }
                m[k] = pk_min(m[k], pk_add(pk_min(lo, hi), t2p));
            }
        }
        done = pk_done(m, 64);
    }
    if (!done) {                         // rare scalar fallback (16 voxels)
        float fm[16];
#pragma unroll
        for (int k = 0; k < 8; ++k) {
            fm[2 * k]     = (float)(m[k] & 0xFFFFu);
            fm[2 * k + 1] = (float)(m[k] >> 16);
        }
        edt_slow16<1, ZD>(&tile[(8 + y0) * TW2 + 8], 16 * ch, fm);
#pragma unroll
        for (int k = 0; k < 8; ++k)
            m[k] = (unsigned int)fm[2 * k] | ((unsigned int)fm[2 * k + 1] << 16);
    }
}

// ------ fused Y+Z EDT + loss accumulation: one (x, class, batch) block -----
// pos plane -> packed EDT -> dpp; re-stage neg in same tile -> packed EDT ->
// phi = (dp==1)?0:sqrt(dn)-sqrt(dp); p*phi block-reduce. No HBM intermediates.
__global__ __launch_bounds__(768) void k_yz_acc(const unsigned char* __restrict__ in,
                                                const __half2* __restrict__ probs,
                                                const int* __restrict__ flags,
                                                double* __restrict__ partials,
                                                int batch0) {
    const int x   = blockIdx.x;
    const int bbl = blockIdx.y / 3;
    const int c   = blockIdx.y % 3;
    const int b   = batch0 + bbl;
    const int tid = threadIdx.x;
    const int pidx = (b * 3 + c) * XD + x;

    __shared__ unsigned short tile[TROWS * TW2];
    __shared__ double sd[768];
    unsigned int* t32 = (unsigned int*)tile;

    if (((flags[b] >> (c + 1)) & 1) == 0) {
        if (tid == 0) partials[pidx] = 0.0;
        return;
    }

    // pads (SENT pairs); EDT write-backs and re-staging touch only data cells
    for (int i = tid; i < 16 * TDW; i += 768) {
        int r = i / TDW, cc = i - r * TDW;
        int row = (r < 8) ? r : 128 + r;
        t32[row * TDW + cc] = SENTP;
    }
    for (int i = tid; i < 128 * 9; i += 768) {
        int r = i / 9, cc = i - r * 9;
        int col = (cc < 4) ? cc : (48 + cc);
        t32[(8 + r) * TDW + col] = SENTP;
    }

    const int zp = tid % 48;  const int iY = (tid / 48) * 8;   // phase Y map
    const int y0 = tid % 128; const int ch = tid / 128;        // phase Z map
    const int e  = tid * 16;
    const int sy = e / ZD, sz = e - sy * ZD;
    const unsigned int sbase = (8 + sy) * TDW + (8 + sz) / 2;

    unsigned int m[8], dpp[8];

    // ================= pos plane (slot 2c) =================
    {
        const uint4* ip = (const uint4*)(in + (size_t)(bbl * 6 + 2 * c) * NV +
                                         (size_t)x * SXX);
        uint4 v = ip[tid];
        unsigned int vv[4] = {v.x, v.y, v.z, v.w};
#pragma unroll
        for (int q = 0; q < 4; ++q) {
            unsigned int b0 = vv[q] & 255u, b1 = (vv[q] >> 8) & 255u;
            unsigned int b2 = (vv[q] >> 16) & 255u, b3 = vv[q] >> 24;
            t32[sbase + 2 * q] = (b0 > 127u ? SENT : b0 * b0) |
                                 ((b1 > 127u ? SENT : b1 * b1) << 16);
            t32[sbase + 2 * q + 1] = (b2 > 127u ? SENT : b2 * b2) |
                                     ((b3 > 127u ? SENT : b3 * b3) << 16);
        }
    }
    __syncthreads();
    edtY_pk(t32, tile, zp, iY, m);
    __syncthreads();                     // all window reads done
    {
        unsigned int* colp = t32 + 4 + zp;
#pragma unroll
        for (int k = 0; k < 8; ++k) colp[(iY + k + 8) * TDW] = m[k];
    }
    __syncthreads();
    edtZ_pk(t32, tile, y0, ch, m);
#pragma unroll
    for (int q = 0; q < 8; ++q) dpp[q] = pk_min(m[q], SENTP);
    __syncthreads();                     // all pos-plane reads done

    // ================= neg plane (slot 2c+1), same tile =================
    {
        const uint4* ip = (const uint4*)(in + (size_t)(bbl * 6 + 2 * c + 1) * NV +
                                         (size_t)x * SXX);
        uint4 v = ip[tid];
        unsigned int vv[4] = {v.x, v.y, v.z, v.w};
#pragma unroll
        for (int q = 0; q < 4; ++q) {
            unsigned int b0 = vv[q] & 255u, b1 = (vv[q] >> 8) & 255u;
            unsigned int b2 = (vv[q] >> 16) & 255u, b3 = vv[q] >> 24;
            t32[sbase + 2 * q] = (b0 > 127u ? SENT : b0 * b0) |
                                 ((b1 > 127u ? SENT : b1 * b1) << 16);
            t32[sbase + 2 * q + 1] = (b2 > 127u ? SENT : b2 * b2) |
                                     ((b3 > 127u ? SENT : b3 * b3) << 16);
        }
    }
    __syncthreads();
    edtY_pk(t32, tile, zp, iY, m);
    __syncthreads();
    {
        unsigned int* colp = t32 + 4 + zp;
#pragma unroll
        for (int k = 0; k < 8; ++k) colp[(iY + k + 8) * TDW] = m[k];
    }
    __syncthreads();
    edtZ_pk(t32, tile, y0, ch, m);       // m = dn^2 (unclamped; clamp below)

    // ================= accumulate p * phi =================
    float a = 0.0f;
    {
        const __half2* pv = probs + (size_t)(b * 3 + c) * (NV / 2) +
                            ((size_t)x * SXX + (size_t)y0 * ZD + 16 * ch) / 2;
#pragma unroll
        for (int q = 0; q < 8; ++q) {
            float2 pf = __half22float2(pv[q]);
            unsigned int dnq = pk_min(m[q], SENTP);
            unsigned int dp0 = dpp[q] & 0xFFFFu, dp1 = dpp[q] >> 16;
            unsigned int dn0 = dnq & 0xFFFFu,   dn1 = dnq >> 16;
            float phi0 = (dp0 == 1u) ? 0.0f
                       : (sqrtf((float)dn0) - sqrtf((float)dp0));
            float phi1 = (dp1 == 1u) ? 0.0f
                       : (sqrtf((float)dn1) - sqrtf((float)dp1));
            a += pf.x * phi0 + pf.y * phi1;
        }
    }
    sd[tid] = (double)a;
    __syncthreads();
    for (int off = 512; off; off >>= 1) {
        if (tid < off && tid + off < 768) sd[tid] += sd[tid + off];
        __syncthreads();
    }
    if (tid == 0) partials[pidx] = sd[0];
}

// -------------------------------------------------------------- reduce ----
__global__ void k_reduce(const double* __restrict__ partials, int n,
                         float* __restrict__ out) {
    __shared__ double sd[256];
    double ls = 0.0;
    for (int i = threadIdx.x; i < n; i += 256) ls += partials[i];
    sd[threadIdx.x] = ls;
    __syncthreads();
    for (int off = 128; off > 0; off >>= 1) {
        if (threadIdx.x < off) sd[threadIdx.x] += sd[threadIdx.x + off];
        __syncthreads();
    }
    if (threadIdx.x == 0) out[0] = (float)(sd[0] / 9437184.0);
}

// ---------------------------------------------------------------- launch ----
extern "C" void kernel_launch(void* const* d_in, const int* in_sizes, int n_in,
                              void* d_out, int out_size, void* d_ws, size_t ws_size,
                              hipStream_t stream) {
    const float* net = (const float*)d_in[0];
    const int*   gt  = (const int*)d_in[1];
    float* out = (float*)d_out;
    char* ws = (char*)d_ws;

    const size_t xbufB1 = (size_t)6 * NV;               // u8 per batch, 9.4 MB
    const size_t probsB = (size_t)2 * 3 * NV * 2;       // f16, both batches
    const size_t tail   = (size_t)768 * sizeof(double) + 64;

    const int nb = (ws_size >= 2 * xbufB1 + probsB + tail) ? 2 : 1;

    unsigned char* xbuf  = (unsigned char*)ws;
    __half2*       probs = (__half2*)(ws + (size_t)nb * xbufB1);
    double*     partials = (double*)((char*)probs + probsB);
    int*           flags = (int*)((char*)partials + 768 * sizeof(double));

    hipMemsetAsync(flags, 0, 8 * sizeof(int), stream);

    for (int b0 = 0; b0 < 2; b0 += nb) {
        hipLaunchKernelGGL(k_scan_prob, dim3(SCANB + PROBB, nb), dim3(384), 0,
                           stream, gt, net, xbuf, probs, flags, b0);
        hipLaunchKernelGGL(k_yz_acc, dim3(XD, 3 * nb), dim3(768), 0, stream,
                           xbuf, probs, flags, partials, b0);
    }
    hipLaunchKernelGGL(k_reduce, dim3(1), dim3(256), 0, stream, partials,
                       768, out);
}

// Round 21
// 68.095 us; speedup vs baseline: 1.2344x; 1.0278x over previous
//
#include <hip/hip_runtime.h>
#include <hip/hip_fp16.h>
#include <math.h>

#define XD 128
#define YD 128
#define ZD 96
#define NV (XD*YD*ZD)      /* 1572864 voxels per volume */
#define SXX (YD*ZD)        /* x-stride = 12288 */
#define SENT 49152         /* sentinel: > any real d^2 (max 41283) */
#define SENTP 0xC000C000u  /* packed pair of SENT */
#define TD3 113            /* dwords per row: 8 pad | 96 z | 9 pad; 113%32=17 */
#define SCANB 192          /* scan blocks per batch */
#define PROBB 1024         /* prob blocks per batch: 1024*384 = NV/4 */

// -------- block-specialized: scan blocks + softmax blocks, one dispatch ----
__global__ __launch_bounds__(384) void k_scan_prob(const int* __restrict__ gt,
                                                   const float* __restrict__ net,
                                                   unsigned char* __restrict__ out,
                                                   __half2* __restrict__ probs,
                                                   int* __restrict__ flags,
                                                   int batch0) {
    const int bb  = blockIdx.y;
    const int myb = batch0 + bb;
    const int tid = threadIdx.x;

    if (blockIdx.x >= SCANB) {           // ---------------- prob role ----
        const int p = (blockIdx.x - SCANB) * 384 + tid;   // quad index < NV/4
        const int idx = p * 4;
        const float* nb = net + (size_t)myb * 4 * NV;
        float4 v0 = *(const float4*)(nb + idx);
        float4 v1 = *(const float4*)(nb + NV + idx);
        float4 v2 = *(const float4*)(nb + 2 * NV + idx);
        float4 v3 = *(const float4*)(nb + 3 * NV + idx);

        const float a0[4] = {v0.x, v0.y, v0.z, v0.w};
        const float a1[4] = {v1.x, v1.y, v1.z, v1.w};
        const float a2[4] = {v2.x, v2.y, v2.z, v2.w};
        const float a3[4] = {v3.x, v3.y, v3.z, v3.w};
        float p1[4], p2[4], p3[4];
#pragma unroll
        for (int j = 0; j < 4; ++j) {
            float mx = fmaxf(fmaxf(a0[j], a1[j]), fmaxf(a2[j], a3[j]));
            float e0 = __expf(a0[j] - mx);
            float e1 = __expf(a1[j] - mx);
            float e2 = __expf(a2[j] - mx);
            float e3 = __expf(a3[j] - mx);
            float iv = __frcp_rn(e0 + e1 + e2 + e3);
            p1[j] = e1 * iv; p2[j] = e2 * iv; p3[j] = e3 * iv;
        }
        probs[(size_t)(myb * 3 + 0) * (NV / 2) + 2 * p]     = __floats2half2_rn(p1[0], p1[1]);
        probs[(size_t)(myb * 3 + 0) * (NV / 2) + 2 * p + 1] = __floats2half2_rn(p1[2], p1[3]);
        probs[(size_t)(myb * 3 + 1) * (NV / 2) + 2 * p]     = __floats2half2_rn(p2[0], p2[1]);
        probs[(size_t)(myb * 3 + 1) * (NV / 2) + 2 * p + 1] = __floats2half2_rn(p2[2], p2[3]);
        probs[(size_t)(myb * 3 + 2) * (NV / 2) + 2 * p]     = __floats2half2_rn(p3[0], p3[1]);
        probs[(size_t)(myb * 3 + 2) * (NV / 2) + 2 * p + 1] = __floats2half2_rn(p3[2], p3[3]);
        return;
    }

    // ---------------- scan role ----
    const int l   = tid & 63;
    const int w6  = tid >> 6;            // 0..5
    const int lq0 = blockIdx.x * 64;

    __shared__ unsigned char gtile[64 * 132];
    __shared__ int blkbits;
    if (tid == 0) blkbits = 0;

    int mybits = 0;
    const int* gp = gt + (size_t)myb * NV + lq0 + l;
    for (int j = w6; j < XD; j += 6) {
        int g = gp[(size_t)j * SXX];
        mybits |= 1 << g;
        gtile[l * 132 + j] = (unsigned char)g;
    }
#pragma unroll
    for (int off = 32; off; off >>= 1) mybits |= __shfl_xor(mybits, off);
    __syncthreads();
    if ((tid & 63) == 0) atomicOr(&blkbits, mybits);

    unsigned int D[32];
    {
        const unsigned int ci = (unsigned int)((w6 >> 1) + 1);
        const int s = w6 & 1;
        unsigned int G[32];
        const unsigned int* grow = (const unsigned int*)gtile + l * 33;
#pragma unroll
        for (int q = 0; q < 32; ++q) G[q] = grow[q];

        int cnt = 200;
#pragma unroll
        for (int q = 0; q < 32; ++q) {
            unsigned int u = G[q], dv = 0;
#pragma unroll
            for (int b = 0; b < 4; ++b) {
                unsigned int gv = (u >> (8 * b)) & 255u;
                bool zero = s ? (gv == ci) : (gv != ci);
                cnt = zero ? 0 : ((cnt < 200) ? cnt + 1 : 200);
                dv |= (unsigned int)cnt << (8 * b);
            }
            D[q] = dv;
        }
        cnt = 200;
#pragma unroll
        for (int q = 31; q >= 0; --q) {
            unsigned int u = G[q], dv = D[q];
#pragma unroll
            for (int b = 3; b >= 0; --b) {
                unsigned int gv = (u >> (8 * b)) & 255u;
                bool zero = s ? (gv == ci) : (gv != ci);
                cnt = zero ? 0 : ((cnt < 200) ? cnt + 1 : 200);
                unsigned int old = (dv >> (8 * b)) & 255u;
                unsigned int nbv = ((unsigned int)cnt < old) ? (unsigned int)cnt : old;
                dv = (dv & ~(255u << (8 * b))) | (nbv << (8 * b));
            }
            D[q] = dv;
        }
    }
    __syncthreads();
    if (tid == 0) atomicOr(&flags[myb], blkbits);

    {   // in-wave 4x4 byte transpose + store
        const int r = l & 3;
        unsigned char* ob = out + (size_t)(bb * 6 + w6) * NV + lq0 + (l & ~3);
#pragma unroll
        for (int q = 0; q < 32; ++q) {
            unsigned int A = D[q];
            unsigned int Bv = (unsigned int)__shfl_xor((int)A, 1);
            unsigned int t = (r & 1)
                ? __builtin_amdgcn_perm(A, Bv, 0x07030501u)
                : __builtin_amdgcn_perm(A, Bv, 0x02060004u);
            unsigned int Cv = (unsigned int)__shfl_xor((int)t, 2);
            unsigned int y = (r & 2)
                ? __builtin_amdgcn_perm(t, Cv, 0x07060302u)
                : __builtin_amdgcn_perm(t, Cv, 0x01000504u);
            *(unsigned int*)(ob + (size_t)(4 * q + r) * SXX) = y;
        }
    }
}

// -------------------- packed-u16 primitives (VOP3P) ------------------------
__device__ __forceinline__ unsigned int pk_min(unsigned int a, unsigned int b) {
    unsigned int d;
    asm("v_pk_min_u16 %0, %1, %2" : "=v"(d) : "v"(a), "v"(b));
    return d;
}
__device__ __forceinline__ unsigned int pk_max(unsigned int a, unsigned int b) {
    unsigned int d;
    asm("v_pk_max_u16 %0, %1, %2" : "=v"(d) : "v"(a), "v"(b));
    return d;
}
__device__ __forceinline__ unsigned int pk_add(unsigned int a, unsigned int b) {
    unsigned int d;
    asm("v_pk_add_u16 %0, %1, %2" : "=v"(d) : "v"(a), "v"(b));
    return d;
}
// values <= 49152+127^2 = 65281 < 2^16: no overflow.

__device__ __forceinline__ bool pk_done16(const unsigned int m[16], int thr) {
    unsigned int mx = m[0];
#pragma unroll
    for (int k = 1; k < 16; ++k) mx = pk_max(mx, m[k]);
    int a = (int)(mx & 0xFFFFu), bq = (int)(mx >> 16);
    int amax = a > bq ? a : bq;
    return __all(amax <= thr) != 0;
}

// ------- scalar slow path (rare; force-inlined, register-resident) ---------
// p0: u16 view, value at j is p0[j*STRIDE]; valid j in [-8, L+7].
template<int STRIDE, int L>
__device__ __forceinline__ void edt_slow16(const unsigned short* __restrict__ p0,
                                           int i0, float m[16]) {
    int t = 9;
    bool done = false;
    while (!done && t < L) {
        for (int u = 0; u < 4; ++u, ++t) {
            float t2 = (float)(t * t);
#pragma unroll
            for (int k = 0; k < 16; ++k) {
                int jm = i0 + k - t; if (jm < -8) jm = -8;
                int jp = i0 + k + t; if (jp > L + 7) jp = L + 7;
                m[k] = fminf(m[k], fminf((float)p0[jm * STRIDE],
                                         (float)p0[jp * STRIDE]) + t2);
            }
        }
        float mm = m[0];
#pragma unroll
        for (int k = 1; k < 16; ++k) mm = fmaxf(mm, m[k]);
        done = __all(mm <= (float)((t - 1) * (t - 1))) != 0;
    }
}

// ------ fused Y+Z EDT + loss: pos|neg packed per voxel in one u32 tile -----
// Tile u32[144 rows = 8|128y|8][113 cols = 8|96z|9]; lo16 = pos d^2, hi16 =
// neg d^2. Every pk op processes BOTH planes of a voxel: one stage pass, one
// Y phase, one Z phase, 4 barriers (vs 8 for sequential planes). No HBM
// intermediates; phi = (dp==1)?0:sqrt(dn)-sqrt(dp); p*phi wave+LDS reduce.
__global__ __launch_bounds__(768) void k_yz_acc(const unsigned char* __restrict__ in,
                                                const __half2* __restrict__ probs,
                                                const int* __restrict__ flags,
                                                double* __restrict__ partials,
                                                int batch0) {
    const int x   = blockIdx.x;
    const int bbl = blockIdx.y / 3;
    const int c   = blockIdx.y % 3;
    const int b   = batch0 + bbl;
    const int tid = threadIdx.x;
    const int pidx = (b * 3 + c) * XD + x;

    __shared__ unsigned int t32[144 * TD3];   // 65088 B
    __shared__ double sd[12];
    unsigned short* t16 = (unsigned short*)t32;

    if (((flags[b] >> (c + 1)) & 1) == 0) {
        if (tid == 0) partials[pidx] = 0.0;
        return;
    }

    // pads: y-pad rows (full width) and z-pad cols in data rows
    for (int i = tid; i < 16 * TD3; i += 768) {
        int r = i / TD3, cc = i - r * TD3;
        int row = (r < 8) ? r : 128 + r;
        t32[row * TD3 + cc] = SENTP;
    }
    for (int i = tid; i < 128 * 17; i += 768) {
        int r = i / 17, cc = i - r * 17;
        int col = (cc < 8) ? cc : (96 + cc);            // 0..7 | 104..112
        t32[(8 + r) * TD3 + col] = SENTP;
    }
    {   // stage both planes: u8 d -> packed (pos|neg) u16 d^2, 16 z per thread
        const uint4* ipP = (const uint4*)(in + (size_t)(bbl * 6 + 2 * c) * NV +
                                          (size_t)x * SXX);
        const uint4* ipN = (const uint4*)(in + (size_t)(bbl * 6 + 2 * c + 1) * NV +
                                          (size_t)x * SXX);
        uint4 vp = ipP[tid], vn = ipN[tid];
        const int sy = tid / 6, sz = 16 * (tid % 6);
        unsigned int* dst = t32 + (8 + sy) * TD3 + 8 + sz;
        unsigned int pp[4] = {vp.x, vp.y, vp.z, vp.w};
        unsigned int nn[4] = {vn.x, vn.y, vn.z, vn.w};
#pragma unroll
        for (int q = 0; q < 4; ++q) {
#pragma unroll
            for (int bq = 0; bq < 4; ++bq) {
                unsigned int pb = (pp[q] >> (8 * bq)) & 255u;
                unsigned int nb2 = (nn[q] >> (8 * bq)) & 255u;
                dst[4 * q + bq] = (pb > 127u ? SENT : pb * pb) |
                                  ((nb2 > 127u ? SENT : nb2 * nb2) << 16);
            }
        }
    }
    __syncthreads();

    unsigned int m[16];
    {   // ---- phase Y: 16 y-outputs at fixed z (lanes vary z: conflict-free)
        const int z0 = tid % 96;
        const int i0 = (tid / 96) * 16;
        unsigned int w[32];
        const unsigned int* colp = t32 + 8 + z0;
#pragma unroll
        for (int q = 0; q < 32; ++q) w[q] = colp[(i0 + q) * TD3];
#pragma unroll
        for (int k = 0; k < 16; ++k) m[k] = w[k + 8];
#pragma unroll
        for (int t = 1; t <= 4; ++t) {
            const unsigned int t2p = (unsigned int)(t * t) * 0x00010001u;
#pragma unroll
            for (int k = 0; k < 16; ++k)
                m[k] = pk_min(m[k], pk_add(pk_min(w[k + 8 - t], w[k + 8 + t]), t2p));
        }
        bool done = pk_done16(m, 16);
        if (!done) {
#pragma unroll
            for (int t = 5; t <= 8; ++t) {
                const unsigned int t2p = (unsigned int)(t * t) * 0x00010001u;
#pragma unroll
                for (int k = 0; k < 16; ++k)
                    m[k] = pk_min(m[k], pk_add(pk_min(w[k + 8 - t], w[k + 8 + t]), t2p));
            }
            done = pk_done16(m, 64);
        }
        if (!done) {                     // rare scalar fallback, per plane
#pragma unroll
            for (int h = 0; h < 2; ++h) {
                float fm[16];
#pragma unroll
                for (int k = 0; k < 16; ++k)
                    fm[k] = (float)(h ? (m[k] >> 16) : (m[k] & 0xFFFFu));
                edt_slow16<2 * TD3, YD>(t16 + (8 * TD3 + 8 + z0) * 2 + h, i0, fm);
#pragma unroll
                for (int k = 0; k < 16; ++k) {
                    unsigned int v = (unsigned int)fm[k];
                    m[k] = h ? ((m[k] & 0x0000FFFFu) | (v << 16))
                             : ((m[k] & 0xFFFF0000u) | v);
                }
            }
        }
        __syncthreads();                 // all window reads done
#pragma unroll
        for (int k = 0; k < 16; ++k)
            t32[(8 + i0 + k) * TD3 + 8 + z0] = pk_min(m[k], SENTP);
        __syncthreads();
    }
    const int y0 = tid % 128;
    const int i0 = (tid / 128) * 16;
    {   // ---- phase Z: 16 z-outputs at fixed y (row stride 113: coprime)
        unsigned int w[32];
        const unsigned int* rowp = t32 + (8 + y0) * TD3 + 8;
#pragma unroll
        for (int q = 0; q < 32; ++q) w[q] = rowp[i0 - 8 + q];
#pragma unroll
        for (int k = 0; k < 16; ++k) m[k] = w[k + 8];
#pragma unroll
        for (int t = 1; t <= 4; ++t) {
            const unsigned int t2p = (unsigned int)(t * t) * 0x00010001u;
#pragma unroll
            for (int k = 0; k < 16; ++k)
                m[k] = pk_min(m[k], pk_add(pk_min(w[k + 8 - t], w[k + 8 + t]), t2p));
        }
        bool done = pk_done16(m, 16);
        if (!done) {
#pragma unroll
            for (int t = 5; t <= 8; ++t) {
                const unsigned int t2p = (unsigned int)(t * t) * 0x00010001u;
#pragma unroll
                for (int k = 0; k < 16; ++k)
                    m[k] = pk_min(m[k], pk_add(pk_min(w[k + 8 - t], w[k + 8 + t]), t2p));
            }
            done = pk_done16(m, 64);
        }
        if (!done) {
#pragma unroll
            for (int h = 0; h < 2; ++h) {
                float fm[16];
#pragma unroll
                for (int k = 0; k < 16; ++k)
                    fm[k] = (float)(h ? (m[k] >> 16) : (m[k] & 0xFFFFu));
                edt_slow16<2, ZD>(t16 + ((8 + y0) * TD3 + 8) * 2 + h, i0, fm);
#pragma unroll
                for (int k = 0; k < 16; ++k) {
                    unsigned int v = (unsigned int)fm[k];
                    m[k] = h ? ((m[k] & 0x0000FFFFu) | (v << 16))
                             : ((m[k] & 0xFFFF0000u) | v);
                }
            }
        }
    }

    // ---- dot with probs (own 16 voxels, contiguous in z) ----
    float a = 0.0f;
    {
        const __half2* pv = probs + (size_t)(b * 3 + c) * (NV / 2) +
                            ((size_t)x * SXX + (size_t)y0 * ZD + i0) / 2;
#pragma unroll
        for (int q = 0; q < 8; ++q) {
            float2 pf = __half22float2(pv[q]);
            unsigned int d0 = pk_min(m[2 * q],     SENTP);
            unsigned int d1 = pk_min(m[2 * q + 1], SENTP);
            unsigned int dp0 = d0 & 0xFFFFu, dn0 = d0 >> 16;
            unsigned int dp1 = d1 & 0xFFFFu, dn1 = d1 >> 16;
            float phi0 = (dp0 == 1u) ? 0.0f
                       : (sqrtf((float)dn0) - sqrtf((float)dp0));
            float phi1 = (dp1 == 1u) ? 0.0f
                       : (sqrtf((float)dn1) - sqrtf((float)dp1));
            a += pf.x * phi0 + pf.y * phi1;
        }
    }
    // ---- wave reduce then 12-slot LDS reduce ----
    double v = (double)a;
#pragma unroll
    for (int off = 32; off; off >>= 1) v += __shfl_down(v, off);
    if ((tid & 63) == 0) sd[tid >> 6] = v;
    __syncthreads();
    if (tid == 0) {
        double s = 0.0;
#pragma unroll
        for (int i = 0; i < 12; ++i) s += sd[i];
        partials[pidx] = s;
    }
}

// -------------------------------------------------------------- reduce ----
__global__ void k_reduce(const double* __restrict__ partials, int n,
                         float* __restrict__ out) {
    __shared__ double sd[256];
    double ls = 0.0;
    for (int i = threadIdx.x; i < n; i += 256) ls += partials[i];
    sd[threadIdx.x] = ls;
    __syncthreads();
    for (int off = 128; off > 0; off >>= 1) {
        if (threadIdx.x < off) sd[threadIdx.x] += sd[threadIdx.x + off];
        __syncthreads();
    }
    if (threadIdx.x == 0) out[0] = (float)(sd[0] / 9437184.0);
}

// ---------------------------------------------------------------- launch ----
extern "C" void kernel_launch(void* const* d_in, const int* in_sizes, int n_in,
                              void* d_out, int out_size, void* d_ws, size_t ws_size,
                              hipStream_t stream) {
    const float* net = (const float*)d_in[0];
    const int*   gt  = (const int*)d_in[1];
    float* out = (float*)d_out;
    char* ws = (char*)d_ws;

    const size_t xbufB1 = (size_t)6 * NV;               // u8 per batch, 9.4 MB
    const size_t probsB = (size_t)2 * 3 * NV * 2;       // f16, both batches
    const size_t tail   = (size_t)768 * sizeof(double) + 64;

    const int nb = (ws_size >= 2 * xbufB1 + probsB + tail) ? 2 : 1;

    unsigned char* xbuf  = (unsigned char*)ws;
    __half2*       probs = (__half2*)(ws + (size_t)nb * xbufB1);
    double*     partials = (double*)((char*)probs + probsB);
    int*           flags = (int*)((char*)partials + 768 * sizeof(double));

    hipMemsetAsync(flags, 0, 8 * sizeof(int), stream);

    for (int b0 = 0; b0 < 2; b0 += nb) {
        hipLaunchKernelGGL(k_scan_prob, dim3(SCANB + PROBB, nb), dim3(384), 0,
                           stream, gt, net, xbuf, probs, flags, b0);
        hipLaunchKernelGGL(k_yz_acc, dim3(XD, 3 * nb), dim3(768), 0, stream,
                           xbuf, probs, flags, partials, b0);
    }
    hipLaunchKernelGGL(k_reduce, dim3(1), dim3(256), 0, stream, partials,
                       768, out);
}

// Round 22
// 67.911 us; speedup vs baseline: 1.2377x; 1.0027x over previous
//
#include <hip/hip_runtime.h>
#include <hip/hip_fp16.h>
#include <math.h>

#define XD 128
#define YD 128
#define ZD 96
#define NV (XD*YD*ZD)      /* 1572864 voxels per volume */
#define SXX (YD*ZD)        /* x-stride = 12288 */
#define SENT 49152         /* sentinel: > any real d^2 (max 41283) */
#define SENTP 0xC000C000u  /* packed pair of SENT */
#define TD3 113            /* dwords per row: 8 pad | 96 z | 9 pad; 113%32=17 */
#define SCANB 192          /* scan blocks per batch */
#define PROBB 1024         /* prob blocks per batch: 1024*384 = NV/4 */

// -------- block-specialized: scan blocks + softmax blocks, one dispatch ----
__global__ __launch_bounds__(384) void k_scan_prob(const int* __restrict__ gt,
                                                   const float* __restrict__ net,
                                                   unsigned char* __restrict__ out,
                                                   __half2* __restrict__ probs,
                                                   int* __restrict__ flags,
                                                   int batch0) {
    const int bb  = blockIdx.y;
    const int myb = batch0 + bb;
    const int tid = threadIdx.x;

    if (blockIdx.x >= SCANB) {           // ---------------- prob role ----
        const int p = (blockIdx.x - SCANB) * 384 + tid;   // quad index < NV/4
        const int idx = p * 4;
        const float* nb = net + (size_t)myb * 4 * NV;
        float4 v0 = *(const float4*)(nb + idx);
        float4 v1 = *(const float4*)(nb + NV + idx);
        float4 v2 = *(const float4*)(nb + 2 * NV + idx);
        float4 v3 = *(const float4*)(nb + 3 * NV + idx);

        const float a0[4] = {v0.x, v0.y, v0.z, v0.w};
        const float a1[4] = {v1.x, v1.y, v1.z, v1.w};
        const float a2[4] = {v2.x, v2.y, v2.z, v2.w};
        const float a3[4] = {v3.x, v3.y, v3.z, v3.w};
        float p1[4], p2[4], p3[4];
#pragma unroll
        for (int j = 0; j < 4; ++j) {
            float mx = fmaxf(fmaxf(a0[j], a1[j]), fmaxf(a2[j], a3[j]));
            float e0 = __expf(a0[j] - mx);
            float e1 = __expf(a1[j] - mx);
            float e2 = __expf(a2[j] - mx);
            float e3 = __expf(a3[j] - mx);
            float iv = __frcp_rn(e0 + e1 + e2 + e3);
            p1[j] = e1 * iv; p2[j] = e2 * iv; p3[j] = e3 * iv;
        }
        probs[(size_t)(myb * 3 + 0) * (NV / 2) + 2 * p]     = __floats2half2_rn(p1[0], p1[1]);
        probs[(size_t)(myb * 3 + 0) * (NV / 2) + 2 * p + 1] = __floats2half2_rn(p1[2], p1[3]);
        probs[(size_t)(myb * 3 + 1) * (NV / 2) + 2 * p]     = __floats2half2_rn(p2[0], p2[1]);
        probs[(size_t)(myb * 3 + 1) * (NV / 2) + 2 * p + 1] = __floats2half2_rn(p2[2], p2[3]);
        probs[(size_t)(myb * 3 + 2) * (NV / 2) + 2 * p]     = __floats2half2_rn(p3[0], p3[1]);
        probs[(size_t)(myb * 3 + 2) * (NV / 2) + 2 * p + 1] = __floats2half2_rn(p3[2], p3[3]);
        return;
    }

    // ---------------- scan role ----
    const int l   = tid & 63;
    const int w6  = tid >> 6;            // 0..5
    const int lq0 = blockIdx.x * 64;

    __shared__ unsigned char gtile[64 * 132];
    __shared__ int blkbits;
    if (tid == 0) blkbits = 0;

    int mybits = 0;
    const int* gp = gt + (size_t)myb * NV + lq0 + l;
    for (int j = w6; j < XD; j += 6) {
        int g = gp[(size_t)j * SXX];
        mybits |= 1 << g;
        gtile[l * 132 + j] = (unsigned char)g;
    }
#pragma unroll
    for (int off = 32; off; off >>= 1) mybits |= __shfl_xor(mybits, off);
    __syncthreads();
    if ((tid & 63) == 0) atomicOr(&blkbits, mybits);

    unsigned int D[32];
    {
        const unsigned int ci = (unsigned int)((w6 >> 1) + 1);
        const int s = w6 & 1;
        unsigned int G[32];
        const unsigned int* grow = (const unsigned int*)gtile + l * 33;
#pragma unroll
        for (int q = 0; q < 32; ++q) G[q] = grow[q];

        int cnt = 200;
#pragma unroll
        for (int q = 0; q < 32; ++q) {
            unsigned int u = G[q], dv = 0;
#pragma unroll
            for (int b = 0; b < 4; ++b) {
                unsigned int gv = (u >> (8 * b)) & 255u;
                bool zero = s ? (gv == ci) : (gv != ci);
                cnt = zero ? 0 : ((cnt < 200) ? cnt + 1 : 200);
                dv |= (unsigned int)cnt << (8 * b);
            }
            D[q] = dv;
        }
        cnt = 200;
#pragma unroll
        for (int q = 31; q >= 0; --q) {
            unsigned int u = G[q], dv = D[q];
#pragma unroll
            for (int b = 3; b >= 0; --b) {
                unsigned int gv = (u >> (8 * b)) & 255u;
                bool zero = s ? (gv == ci) : (gv != ci);
                cnt = zero ? 0 : ((cnt < 200) ? cnt + 1 : 200);
                unsigned int old = (dv >> (8 * b)) & 255u;
                unsigned int nbv = ((unsigned int)cnt < old) ? (unsigned int)cnt : old;
                dv = (dv & ~(255u << (8 * b))) | (nbv << (8 * b));
            }
            D[q] = dv;
        }
    }
    __syncthreads();
    if (tid == 0) atomicOr(&flags[myb], blkbits);

    {   // in-wave 4x4 byte transpose + store
        const int r = l & 3;
        unsigned char* ob = out + (size_t)(bb * 6 + w6) * NV + lq0 + (l & ~3);
#pragma unroll
        for (int q = 0; q < 32; ++q) {
            unsigned int A = D[q];
            unsigned int Bv = (unsigned int)__shfl_xor((int)A, 1);
            unsigned int t = (r & 1)
                ? __builtin_amdgcn_perm(A, Bv, 0x07030501u)
                : __builtin_amdgcn_perm(A, Bv, 0x02060004u);
            unsigned int Cv = (unsigned int)__shfl_xor((int)t, 2);
            unsigned int y = (r & 2)
                ? __builtin_amdgcn_perm(t, Cv, 0x07060302u)
                : __builtin_amdgcn_perm(t, Cv, 0x01000504u);
            *(unsigned int*)(ob + (size_t)(4 * q + r) * SXX) = y;
        }
    }
}

// -------------------- packed-u16 primitives (VOP3P) ------------------------
__device__ __forceinline__ unsigned int pk_min(unsigned int a, unsigned int b) {
    unsigned int d;
    asm("v_pk_min_u16 %0, %1, %2" : "=v"(d) : "v"(a), "v"(b));
    return d;
}
__device__ __forceinline__ unsigned int pk_max(unsigned int a, unsigned int b) {
    unsigned int d;
    asm("v_pk_max_u16 %0, %1, %2" : "=v"(d) : "v"(a), "v"(b));
    return d;
}
__device__ __forceinline__ unsigned int pk_add(unsigned int a, unsigned int b) {
    unsigned int d;
    asm("v_pk_add_u16 %0, %1, %2" : "=v"(d) : "v"(a), "v"(b));
    return d;
}
// values <= 49152+127^2 = 65281 < 2^16: no overflow. m[k] <= SENT invariant
// (starts at staged value <= SENT, only decreases) -> no clamps needed.

__device__ __forceinline__ bool pk_done16(const unsigned int m[16], int thr) {
    unsigned int mx = m[0];
#pragma unroll
    for (int k = 1; k < 16; ++k) mx = pk_max(mx, m[k]);
    int a = (int)(mx & 0xFFFFu), bq = (int)(mx >> 16);
    int amax = a > bq ? a : bq;
    return __all(amax <= thr) != 0;
}

// ------- scalar slow path (rare; force-inlined, register-resident) ---------
template<int STRIDE, int L>
__device__ __forceinline__ void edt_slow16(const unsigned short* __restrict__ p0,
                                           int i0, float m[16]) {
    int t = 9;
    bool done = false;
    while (!done && t < L) {
        for (int u = 0; u < 4; ++u, ++t) {
            float t2 = (float)(t * t);
#pragma unroll
            for (int k = 0; k < 16; ++k) {
                int jm = i0 + k - t; if (jm < -8) jm = -8;
                int jp = i0 + k + t; if (jp > L + 7) jp = L + 7;
                m[k] = fminf(m[k], fminf((float)p0[jm * STRIDE],
                                         (float)p0[jp * STRIDE]) + t2);
            }
        }
        float mm = m[0];
#pragma unroll
        for (int k = 1; k < 16; ++k) mm = fmaxf(mm, m[k]);
        done = __all(mm <= (float)((t - 1) * (t - 1))) != 0;
    }
}

// ---- packed EDT core: 24-dword hot window (t<=4, ~99.9% exit), 8 extra ----
// dwords loaded lazily for t=5..8, scalar slow path beyond. LDSF(j) must
// yield the packed dword at line position j (valid j in [-8, L+7]).
#define EDT_PK_PHASE(LDSF, T16BASE, T16STRIDE, LCAP, i0, m)                     \
    {                                                                           \
        unsigned int w[24];                                                     \
        _Pragma("unroll")                                                       \
        for (int q = 0; q < 24; ++q) w[q] = LDSF((i0) - 4 + q);                 \
        _Pragma("unroll")                                                       \
        for (int k = 0; k < 16; ++k) m[k] = w[k + 4];                           \
        _Pragma("unroll")                                                       \
        for (int t = 1; t <= 4; ++t) {                                          \
            const unsigned int t2p = (unsigned int)(t * t) * 0x00010001u;       \
            _Pragma("unroll")                                                   \
            for (int k = 0; k < 16; ++k)                                        \
                m[k] = pk_min(m[k],                                             \
                              pk_add(pk_min(w[k + 4 - t], w[k + 4 + t]), t2p)); \
        }                                                                       \
        bool done = pk_done16(m, 16);                                           \
        if (!done) {                                                            \
            unsigned int wlo[4], whi[4];                                        \
            _Pragma("unroll")                                                   \
            for (int q = 0; q < 4; ++q) {                                       \
                wlo[q] = LDSF((i0) - 8 + q);                                    \
                whi[q] = LDSF((i0) + 20 + q);                                   \
            }                                                                   \
            _Pragma("unroll")                                                   \
            for (int t = 5; t <= 8; ++t) {                                      \
                const unsigned int t2p = (unsigned int)(t * t) * 0x00010001u;   \
                _Pragma("unroll")                                               \
                for (int k = 0; k < 16; ++k) {                                  \
                    unsigned int lo = (k - t >= -4) ? w[k - t + 4]              \
                                                    : wlo[k - t + 8];           \
                    unsigned int hi = (k + t <= 19) ? w[k + t + 4]              \
                                                    : whi[k + t - 20];          \
                    m[k] = pk_min(m[k], pk_add(pk_min(lo, hi), t2p));           \
                }                                                               \
            }                                                                   \
            done = pk_done16(m, 64);                                            \
        }                                                                       \
        if (!done) {                                                            \
            _Pragma("unroll")                                                   \
            for (int h = 0; h < 2; ++h) {                                       \
                float fm[16];                                                   \
                _Pragma("unroll")                                               \
                for (int k = 0; k < 16; ++k)                                    \
                    fm[k] = (float)(h ? (m[k] >> 16) : (m[k] & 0xFFFFu));       \
                edt_slow16<(T16STRIDE), (LCAP)>((T16BASE) + h, i0, fm);         \
                _Pragma("unroll")                                               \
                for (int k = 0; k < 16; ++k) {                                  \
                    unsigned int v = (unsigned int)fm[k];                       \
                    m[k] = h ? ((m[k] & 0x0000FFFFu) | (v << 16))               \
                             : ((m[k] & 0xFFFF0000u) | v);                      \
                }                                                               \
            }                                                                   \
        }                                                                       \
    }

// ------ fused Y+Z EDT + loss: pos|neg packed per voxel in one u32 tile -----
__global__ __launch_bounds__(768) void k_yz_acc(const unsigned char* __restrict__ in,
                                                const __half2* __restrict__ probs,
                                                const int* __restrict__ flags,
                                                double* __restrict__ partials,
                                                int batch0) {
    const int x   = blockIdx.x;
    const int bbl = blockIdx.y / 3;
    const int c   = blockIdx.y % 3;
    const int b   = batch0 + bbl;
    const int tid = threadIdx.x;
    const int pidx = (b * 3 + c) * XD + x;

    __shared__ unsigned int t32[144 * TD3];   // 65088 B
    __shared__ double sd[12];
    unsigned short* t16 = (unsigned short*)t32;

    if (((flags[b] >> (c + 1)) & 1) == 0) {
        if (tid == 0) partials[pidx] = 0.0;
        return;
    }

    // pads: y-pad rows (full width) and z-pad cols in data rows
    for (int i = tid; i < 16 * TD3; i += 768) {
        int r = i / TD3, cc = i - r * TD3;
        int row = (r < 8) ? r : 128 + r;
        t32[row * TD3 + cc] = SENTP;
    }
    for (int i = tid; i < 128 * 17; i += 768) {
        int r = i / 17, cc = i - r * 17;
        int col = (cc < 8) ? cc : (96 + cc);            // 0..7 | 104..112
        t32[(8 + r) * TD3 + col] = SENTP;
    }
    {   // stage both planes: u8 d -> packed (pos|neg) u16 d^2, 16 z per thread
        const uint4* ipP = (const uint4*)(in + (size_t)(bbl * 6 + 2 * c) * NV +
                                          (size_t)x * SXX);
        const uint4* ipN = (const uint4*)(in + (size_t)(bbl * 6 + 2 * c + 1) * NV +
                                          (size_t)x * SXX);
        uint4 vp = ipP[tid], vn = ipN[tid];
        const int sy = tid / 6, sz = 16 * (tid % 6);
        unsigned int* dst = t32 + (8 + sy) * TD3 + 8 + sz;
        unsigned int pp[4] = {vp.x, vp.y, vp.z, vp.w};
        unsigned int nn[4] = {vn.x, vn.y, vn.z, vn.w};
#pragma unroll
        for (int q = 0; q < 4; ++q) {
#pragma unroll
            for (int bq = 0; bq < 4; ++bq) {
                unsigned int pb = (pp[q] >> (8 * bq)) & 255u;
                unsigned int nb2 = (nn[q] >> (8 * bq)) & 255u;
                dst[4 * q + bq] = (pb > 127u ? SENT : pb * pb) |
                                  ((nb2 > 127u ? SENT : nb2 * nb2) << 16);
            }
        }
    }
    __syncthreads();

    unsigned int m[16];
    {   // ---- phase Y: 16 y-outputs at fixed z (lanes vary z: conflict-free)
        const int z0 = tid % 96;
        const int i0 = (tid / 96) * 16;
        const unsigned int* colp = t32 + 8 + z0;
#define LDY(j) colp[((j) + 8) * TD3]
        EDT_PK_PHASE(LDY, t16 + (8 * TD3 + 8 + z0) * 2, 2 * TD3, YD, i0, m)
#undef LDY
        __syncthreads();                 // all window reads done
#pragma unroll
        for (int k = 0; k < 16; ++k)
            t32[(8 + i0 + k) * TD3 + 8 + z0] = m[k];
        __syncthreads();
    }
    const int y0 = tid % 128;
    const int i0 = (tid / 128) * 16;
    {   // ---- phase Z: 16 z-outputs at fixed y (row stride 113: coprime)
        const unsigned int* rowp = t32 + (8 + y0) * TD3 + 8;
#define LDZ(j) rowp[(j)]
        EDT_PK_PHASE(LDZ, t16 + ((8 + y0) * TD3 + 8) * 2, 2, ZD, i0, m)
#undef LDZ
    }

    // ---- dot with probs (own 16 voxels, contiguous in z) ----
    float a = 0.0f;
    {
        const __half2* pv = probs + (size_t)(b * 3 + c) * (NV / 2) +
                            ((size_t)x * SXX + (size_t)y0 * ZD + i0) / 2;
#pragma unroll
        for (int q = 0; q < 8; ++q) {
            float2 pf = __half22float2(pv[q]);
            unsigned int d0 = m[2 * q];
            unsigned int d1 = m[2 * q + 1];
            unsigned int dp0 = d0 & 0xFFFFu, dn0 = d0 >> 16;
            unsigned int dp1 = d1 & 0xFFFFu, dn1 = d1 >> 16;
            float phi0 = (dp0 == 1u) ? 0.0f
                       : (sqrtf((float)dn0) - sqrtf((float)dp0));
            float phi1 = (dp1 == 1u) ? 0.0f
                       : (sqrtf((float)dn1) - sqrtf((float)dp1));
            a += pf.x * phi0 + pf.y * phi1;
        }
    }
    // ---- wave reduce then 12-slot LDS reduce ----
    double v = (double)a;
#pragma unroll
    for (int off = 32; off; off >>= 1) v += __shfl_down(v, off);
    if ((tid & 63) == 0) sd[tid >> 6] = v;
    __syncthreads();
    if (tid == 0) {
        double s = 0.0;
#pragma unroll
        for (int i = 0; i < 12; ++i) s += sd[i];
        partials[pidx] = s;
    }
}

// -------------------------------------------------------------- reduce ----
__global__ void k_reduce(const double* __restrict__ partials, int n,
                         float* __restrict__ out) {
    __shared__ double sd[256];
    double ls = 0.0;
    for (int i = threadIdx.x; i < n; i += 256) ls += partials[i];
    sd[threadIdx.x] = ls;
    __syncthreads();
    for (int off = 128; off > 0; off >>= 1) {
        if (threadIdx.x < off) sd[threadIdx.x] += sd[threadIdx.x + off];
        __syncthreads();
    }
    if (threadIdx.x == 0) out[0] = (float)(sd[0] / 9437184.0);
}

// ---------------------------------------------------------------- launch ----
extern "C" void kernel_launch(void* const* d_in, const int* in_sizes, int n_in,
                              void* d_out, int out_size, void* d_ws, size_t ws_size,
                              hipStream_t stream) {
    const float* net = (const float*)d_in[0];
    const int*   gt  = (const int*)d_in[1];
    float* out = (float*)d_out;
    char* ws = (char*)d_ws;

    const size_t xbufB1 = (size_t)6 * NV;               // u8 per batch, 9.4 MB
    const size_t probsB = (size_t)2 * 3 * NV * 2;       // f16, both batches
    const size_t tail   = (size_t)768 * sizeof(double) + 64;

    const int nb = (ws_size >= 2 * xbufB1 + probsB + tail) ? 2 : 1;

    unsigned char* xbuf  = (unsigned char*)ws;
    __half2*       probs = (__half2*)(ws + (size_t)nb * xbufB1);
    double*     partials = (double*)((char*)probs + probsB);
    int*           flags = (int*)((char*)partials + 768 * sizeof(double));

    hipMemsetAsync(flags, 0, 8 * sizeof(int), stream);

    for (int b0 = 0; b0 < 2; b0 += nb) {
        hipLaunchKernelGGL(k_scan_prob, dim3(SCANB + PROBB, nb), dim3(384), 0,
                           stream, gt, net, xbuf, probs, flags, b0);
        hipLaunchKernelGGL(k_yz_acc, dim3(XD, 3 * nb), dim3(768), 0, stream,
                           xbuf, probs, flags, partials, b0);
    }
    hipLaunchKernelGGL(k_reduce, dim3(1), dim3(256), 0, stream, partials,
                       768, out);
}

// Round 23
// 67.434 us; speedup vs baseline: 1.2465x; 1.0071x over previous
//
#include <hip/hip_runtime.h>
#include <hip/hip_fp16.h>
#include <math.h>

#define XD 128
#define YD 128
#define ZD 96
#define NV (XD*YD*ZD)      /* 1572864 voxels per volume */
#define SXX (YD*ZD)        /* x-stride = 12288 */
#define SENT 49152         /* sentinel: > any real d^2 (max 41283) */
#define SENTP 0xC000C000u  /* packed pair of SENT */
#define TD3 113            /* dwords per row: 8 pad | 96 z | 9 pad; 113%32=17 */
#define SCANB 192          /* scan blocks per batch */
#define PROBB 1024         /* prob blocks per batch: 1024*384 = NV/4 */

// -------- block-specialized: scan blocks + softmax blocks, one dispatch ----
__global__ __launch_bounds__(384) void k_scan_prob(const int* __restrict__ gt,
                                                   const float* __restrict__ net,
                                                   unsigned char* __restrict__ out,
                                                   __half2* __restrict__ probs,
                                                   int* __restrict__ flags,
                                                   int batch0) {
    const int bb  = blockIdx.y;
    const int myb = batch0 + bb;
    const int tid = threadIdx.x;

    if (blockIdx.x >= SCANB) {           // ---------------- prob role ----
        const int p = (blockIdx.x - SCANB) * 384 + tid;   // quad index < NV/4
        const int idx = p * 4;
        const float* nb = net + (size_t)myb * 4 * NV;
        float4 v0 = *(const float4*)(nb + idx);
        float4 v1 = *(const float4*)(nb + NV + idx);
        float4 v2 = *(const float4*)(nb + 2 * NV + idx);
        float4 v3 = *(const float4*)(nb + 3 * NV + idx);

        const float a0[4] = {v0.x, v0.y, v0.z, v0.w};
        const float a1[4] = {v1.x, v1.y, v1.z, v1.w};
        const float a2[4] = {v2.x, v2.y, v2.z, v2.w};
        const float a3[4] = {v3.x, v3.y, v3.z, v3.w};
        float p1[4], p2[4], p3[4];
#pragma unroll
        for (int j = 0; j < 4; ++j) {
            float mx = fmaxf(fmaxf(a0[j], a1[j]), fmaxf(a2[j], a3[j]));
            float e0 = __expf(a0[j] - mx);
            float e1 = __expf(a1[j] - mx);
            float e2 = __expf(a2[j] - mx);
            float e3 = __expf(a3[j] - mx);
            float iv = __frcp_rn(e0 + e1 + e2 + e3);
            p1[j] = e1 * iv; p2[j] = e2 * iv; p3[j] = e3 * iv;
        }
        probs[(size_t)(myb * 3 + 0) * (NV / 2) + 2 * p]     = __floats2half2_rn(p1[0], p1[1]);
        probs[(size_t)(myb * 3 + 0) * (NV / 2) + 2 * p + 1] = __floats2half2_rn(p1[2], p1[3]);
        probs[(size_t)(myb * 3 + 1) * (NV / 2) + 2 * p]     = __floats2half2_rn(p2[0], p2[1]);
        probs[(size_t)(myb * 3 + 1) * (NV / 2) + 2 * p + 1] = __floats2half2_rn(p2[2], p2[3]);
        probs[(size_t)(myb * 3 + 2) * (NV / 2) + 2 * p]     = __floats2half2_rn(p3[0], p3[1]);
        probs[(size_t)(myb * 3 + 2) * (NV / 2) + 2 * p + 1] = __floats2half2_rn(p3[2], p3[3]);
        return;
    }

    // ---------------- scan role ----
    const int l   = tid & 63;
    const int w6  = tid >> 6;            // 0..5
    const int lq0 = blockIdx.x * 64;

    __shared__ unsigned char gtile[64 * 132];
    __shared__ int blkbits;
    if (tid == 0) blkbits = 0;

    int mybits = 0;
    const int* gp = gt + (size_t)myb * NV + lq0 + l;
    for (int j = w6; j < XD; j += 6) {
        int g = gp[(size_t)j * SXX];
        mybits |= 1 << g;
        gtile[l * 132 + j] = (unsigned char)g;
    }
#pragma unroll
    for (int off = 32; off; off >>= 1) mybits |= __shfl_xor(mybits, off);
    __syncthreads();
    if ((tid & 63) == 0) atomicOr(&blkbits, mybits);

    unsigned int D[32];
    {
        const unsigned int ci = (unsigned int)((w6 >> 1) + 1);
        const int s = w6 & 1;
        unsigned int G[32];
        const unsigned int* grow = (const unsigned int*)gtile + l * 33;
#pragma unroll
        for (int q = 0; q < 32; ++q) G[q] = grow[q];

        int cnt = 200;
#pragma unroll
        for (int q = 0; q < 32; ++q) {
            unsigned int u = G[q], dv = 0;
#pragma unroll
            for (int b = 0; b < 4; ++b) {
                unsigned int gv = (u >> (8 * b)) & 255u;
                bool zero = s ? (gv == ci) : (gv != ci);
                cnt = zero ? 0 : ((cnt < 200) ? cnt + 1 : 200);
                dv |= (unsigned int)cnt << (8 * b);
            }
            D[q] = dv;
        }
        cnt = 200;
#pragma unroll
        for (int q = 31; q >= 0; --q) {
            unsigned int u = G[q], dv = D[q];
#pragma unroll
            for (int b = 3; b >= 0; --b) {
                unsigned int gv = (u >> (8 * b)) & 255u;
                bool zero = s ? (gv == ci) : (gv != ci);
                cnt = zero ? 0 : ((cnt < 200) ? cnt + 1 : 200);
                unsigned int old = (dv >> (8 * b)) & 255u;
                unsigned int nbv = ((unsigned int)cnt < old) ? (unsigned int)cnt : old;
                dv = (dv & ~(255u << (8 * b))) | (nbv << (8 * b));
            }
            D[q] = dv;
        }
    }
    __syncthreads();
    if (tid == 0) atomicOr(&flags[myb], blkbits);

    {   // in-wave 4x4 byte transpose + store
        const int r = l & 3;
        unsigned char* ob = out + (size_t)(bb * 6 + w6) * NV + lq0 + (l & ~3);
#pragma unroll
        for (int q = 0; q < 32; ++q) {
            unsigned int A = D[q];
            unsigned int Bv = (unsigned int)__shfl_xor((int)A, 1);
            unsigned int t = (r & 1)
                ? __builtin_amdgcn_perm(A, Bv, 0x07030501u)
                : __builtin_amdgcn_perm(A, Bv, 0x02060004u);
            unsigned int Cv = (unsigned int)__shfl_xor((int)t, 2);
            unsigned int y = (r & 2)
                ? __builtin_amdgcn_perm(t, Cv, 0x07060302u)
                : __builtin_amdgcn_perm(t, Cv, 0x01000504u);
            *(unsigned int*)(ob + (size_t)(4 * q + r) * SXX) = y;
        }
    }
}

// -------------------- packed-u16 primitives (VOP3P) ------------------------
__device__ __forceinline__ unsigned int pk_min(unsigned int a, unsigned int b) {
    unsigned int d;
    asm("v_pk_min_u16 %0, %1, %2" : "=v"(d) : "v"(a), "v"(b));
    return d;
}
__device__ __forceinline__ unsigned int pk_max(unsigned int a, unsigned int b) {
    unsigned int d;
    asm("v_pk_max_u16 %0, %1, %2" : "=v"(d) : "v"(a), "v"(b));
    return d;
}
__device__ __forceinline__ unsigned int pk_add(unsigned int a, unsigned int b) {
    unsigned int d;
    asm("v_pk_add_u16 %0, %1, %2" : "=v"(d) : "v"(a), "v"(b));
    return d;
}
// values <= 49152+127^2 = 65281 < 2^16: no overflow. m[k] <= SENT invariant
// (starts at staged value <= SENT, only decreases) -> no clamps needed.

__device__ __forceinline__ bool pk_done16(const unsigned int m[16], int thr) {
    unsigned int mx = m[0];
#pragma unroll
    for (int k = 1; k < 16; ++k) mx = pk_max(mx, m[k]);
    int a = (int)(mx & 0xFFFFu), bq = (int)(mx >> 16);
    int amax = a > bq ? a : bq;
    return __all(amax <= thr) != 0;
}

// ------- scalar slow path (rare; force-inlined, register-resident) ---------
template<int STRIDE, int L>
__device__ __forceinline__ void edt_slow16(const unsigned short* __restrict__ p0,
                                           int i0, float m[16]) {
    int t = 9;
    bool done = false;
    while (!done && t < L) {
        for (int u = 0; u < 4; ++u, ++t) {
            float t2 = (float)(t * t);
#pragma unroll
            for (int k = 0; k < 16; ++k) {
                int jm = i0 + k - t; if (jm < -8) jm = -8;
                int jp = i0 + k + t; if (jp > L + 7) jp = L + 7;
                m[k] = fminf(m[k], fminf((float)p0[jm * STRIDE],
                                         (float)p0[jp * STRIDE]) + t2);
            }
        }
        float mm = m[0];
#pragma unroll
        for (int k = 1; k < 16; ++k) mm = fmaxf(mm, m[k]);
        done = __all(mm <= (float)((t - 1) * (t - 1))) != 0;
    }
}

// ---- packed EDT core: 24-dword hot window (t<=4, ~99.9% exit), 8 extra ----
// dwords loaded lazily for t=5..8, scalar slow path beyond. LDSF(j) must
// yield the packed dword at line position j (valid j in [-8, L+7]).
#define EDT_PK_PHASE(LDSF, T16BASE, T16STRIDE, LCAP, i0, m)                     \
    {                                                                           \
        unsigned int w[24];                                                     \
        _Pragma("unroll")                                                       \
        for (int q = 0; q < 24; ++q) w[q] = LDSF((i0) - 4 + q);                 \
        _Pragma("unroll")                                                       \
        for (int k = 0; k < 16; ++k) m[k] = w[k + 4];                           \
        _Pragma("unroll")                                                       \
        for (int t = 1; t <= 4; ++t) {                                          \
            const unsigned int t2p = (unsigned int)(t * t) * 0x00010001u;       \
            _Pragma("unroll")                                                   \
            for (int k = 0; k < 16; ++k)                                        \
                m[k] = pk_min(m[k],                                             \
                              pk_add(pk_min(w[k + 4 - t], w[k + 4 + t]), t2p)); \
        }                                                                       \
        bool done = pk_done16(m, 16);                                           \
        if (!done) {                                                            \
            unsigned int wlo[4], whi[4];                                        \
            _Pragma("unroll")                                                   \
            for (int q = 0; q < 4; ++q) {                                       \
                wlo[q] = LDSF((i0) - 8 + q);                                    \
                whi[q] = LDSF((i0) + 20 + q);                                   \
            }                                                                   \
            _Pragma("unroll")                                                   \
            for (int t = 5; t <= 8; ++t) {                                      \
                const unsigned int t2p = (unsigned int)(t * t) * 0x00010001u;   \
                _Pragma("unroll")                                               \
                for (int k = 0; k < 16; ++k) {                                  \
                    unsigned int lo = (k - t >= -4) ? w[k - t + 4]              \
                                                    : wlo[k - t + 8];           \
                    unsigned int hi = (k + t <= 19) ? w[k + t + 4]              \
                                                    : whi[k + t - 20];          \
                    m[k] = pk_min(m[k], pk_add(pk_min(lo, hi), t2p));           \
                }                                                               \
            }                                                                   \
            done = pk_done16(m, 64);                                            \
        }                                                                       \
        if (!done) {                                                            \
            _Pragma("unroll")                                                   \
            for (int h = 0; h < 2; ++h) {                                       \
                float fm[16];                                                   \
                _Pragma("unroll")                                               \
                for (int k = 0; k < 16; ++k)                                    \
                    fm[k] = (float)(h ? (m[k] >> 16) : (m[k] & 0xFFFFu));       \
                edt_slow16<(T16STRIDE), (LCAP)>((T16BASE) + h, i0, fm);         \
                _Pragma("unroll")                                               \
                for (int k = 0; k < 16; ++k) {                                  \
                    unsigned int v = (unsigned int)fm[k];                       \
                    m[k] = h ? ((m[k] & 0x0000FFFFu) | (v << 16))               \
                             : ((m[k] & 0xFFFF0000u) | v);                      \
                }                                                               \
            }                                                                   \
        }                                                                       \
    }

// ------ fused Y+Z EDT + loss: pos|neg packed per voxel in one u32 tile -----
// Latency hiding: stage uint4 loads issued BEFORE the pad fill; probs
// prefetched into registers before phase Z (consumed after it).
__global__ __launch_bounds__(768) void k_yz_acc(const unsigned char* __restrict__ in,
                                                const __half2* __restrict__ probs,
                                                const int* __restrict__ flags,
                                                double* __restrict__ partials,
                                                int batch0) {
    const int x   = blockIdx.x;
    const int bbl = blockIdx.y / 3;
    const int c   = blockIdx.y % 3;
    const int b   = batch0 + bbl;
    const int tid = threadIdx.x;
    const int pidx = (b * 3 + c) * XD + x;

    __shared__ unsigned int t32[144 * TD3];   // 65088 B
    __shared__ double sd[12];
    unsigned short* t16 = (unsigned short*)t32;

    if (((flags[b] >> (c + 1)) & 1) == 0) {
        if (tid == 0) partials[pidx] = 0.0;
        return;
    }

    // issue stage loads first: latency overlaps the pad fill below
    const uint4* ipP = (const uint4*)(in + (size_t)(bbl * 6 + 2 * c) * NV +
                                      (size_t)x * SXX);
    const uint4* ipN = (const uint4*)(in + (size_t)(bbl * 6 + 2 * c + 1) * NV +
                                      (size_t)x * SXX);
    uint4 vp = ipP[tid], vn = ipN[tid];

    // pads: y-pad rows (full width) and z-pad cols in data rows
    for (int i = tid; i < 16 * TD3; i += 768) {
        int r = i / TD3, cc = i - r * TD3;
        int row = (r < 8) ? r : 128 + r;
        t32[row * TD3 + cc] = SENTP;
    }
    for (int i = tid; i < 128 * 17; i += 768) {
        int r = i / 17, cc = i - r * 17;
        int col = (cc < 8) ? cc : (96 + cc);            // 0..7 | 104..112
        t32[(8 + r) * TD3 + col] = SENTP;
    }
    {   // unpack both planes: u8 d -> packed (pos|neg) u16 d^2, 16 z/thread
        const int sy = tid / 6, sz = 16 * (tid % 6);
        unsigned int* dst = t32 + (8 + sy) * TD3 + 8 + sz;
        unsigned int pp[4] = {vp.x, vp.y, vp.z, vp.w};
        unsigned int nn[4] = {vn.x, vn.y, vn.z, vn.w};
#pragma unroll
        for (int q = 0; q < 4; ++q) {
#pragma unroll
            for (int bq = 0; bq < 4; ++bq) {
                unsigned int pb = (pp[q] >> (8 * bq)) & 255u;
                unsigned int nb2 = (nn[q] >> (8 * bq)) & 255u;
                dst[4 * q + bq] = (pb > 127u ? SENT : pb * pb) |
                                  ((nb2 > 127u ? SENT : nb2 * nb2) << 16);
            }
        }
    }
    __syncthreads();

    unsigned int m[16];
    {   // ---- phase Y: 16 y-outputs at fixed z (lanes vary z: conflict-free)
        const int z0 = tid % 96;
        const int i0 = (tid / 96) * 16;
        const unsigned int* colp = t32 + 8 + z0;
#define LDY(j) colp[((j) + 8) * TD3]
        EDT_PK_PHASE(LDY, t16 + (8 * TD3 + 8 + z0) * 2, 2 * TD3, YD, i0, m)
#undef LDY
        __syncthreads();                 // all window reads done
#pragma unroll
        for (int k = 0; k < 16; ++k)
            t32[(8 + i0 + k) * TD3 + 8 + z0] = m[k];
        __syncthreads();
    }
    const int y0 = tid % 128;
    const int i0 = (tid / 128) * 16;

    // prefetch probs now: HBM latency hides under all of phase Z
    uint4 pr0, pr1;
    {
        const __half2* pv = probs + (size_t)(b * 3 + c) * (NV / 2) +
                            ((size_t)x * SXX + (size_t)y0 * ZD + i0) / 2;
        pr0 = *(const uint4*)pv;
        pr1 = *(const uint4*)(pv + 4);
    }

    {   // ---- phase Z: 16 z-outputs at fixed y (row stride 113: coprime)
        const unsigned int* rowp = t32 + (8 + y0) * TD3 + 8;
#define LDZ(j) rowp[(j)]
        EDT_PK_PHASE(LDZ, t16 + ((8 + y0) * TD3 + 8) * 2, 2, ZD, i0, m)
#undef LDZ
    }

    // ---- dot with prefetched probs (own 16 voxels, contiguous in z) ----
    float a = 0.0f;
    {
        unsigned int pw[8] = {pr0.x, pr0.y, pr0.z, pr0.w,
                              pr1.x, pr1.y, pr1.z, pr1.w};
#pragma unroll
        for (int q = 0; q < 8; ++q) {
            float2 pf = __half22float2(*reinterpret_cast<const __half2*>(&pw[q]));
            unsigned int d0 = m[2 * q];
            unsigned int d1 = m[2 * q + 1];
            unsigned int dp0 = d0 & 0xFFFFu, dn0 = d0 >> 16;
            unsigned int dp1 = d1 & 0xFFFFu, dn1 = d1 >> 16;
            float phi0 = (dp0 == 1u) ? 0.0f
                       : (sqrtf((float)dn0) - sqrtf((float)dp0));
            float phi1 = (dp1 == 1u) ? 0.0f
                       : (sqrtf((float)dn1) - sqrtf((float)dp1));
            a += pf.x * phi0 + pf.y * phi1;
        }
    }
    // ---- wave reduce then 12-slot LDS reduce ----
    double v = (double)a;
#pragma unroll
    for (int off = 32; off; off >>= 1) v += __shfl_down(v, off);
    if ((tid & 63) == 0) sd[tid >> 6] = v;
    __syncthreads();
    if (tid == 0) {
        double s = 0.0;
#pragma unroll
        for (int i = 0; i < 12; ++i) s += sd[i];
        partials[pidx] = s;
    }
}

// -------------------------------------------------------------- reduce ----
__global__ void k_reduce(const double* __restrict__ partials, int n,
                         float* __restrict__ out) {
    __shared__ double sd[256];
    double ls = 0.0;
    for (int i = threadIdx.x; i < n; i += 256) ls += partials[i];
    sd[threadIdx.x] = ls;
    __syncthreads();
    for (int off = 128; off > 0; off >>= 1) {
        if (threadIdx.x < off) sd[threadIdx.x] += sd[threadIdx.x + off];
        __syncthreads();
    }
    if (threadIdx.x == 0) out[0] = (float)(sd[0] / 9437184.0);
}

// ---------------------------------------------------------------- launch ----
extern "C" void kernel_launch(void* const* d_in, const int* in_sizes, int n_in,
                              void* d_out, int out_size, void* d_ws, size_t ws_size,
                              hipStream_t stream) {
    const float* net = (const float*)d_in[0];
    const int*   gt  = (const int*)d_in[1];
    float* out = (float*)d_out;
    char* ws = (char*)d_ws;

    const size_t xbufB1 = (size_t)6 * NV;               // u8 per batch, 9.4 MB
    const size_t probsB = (size_t)2 * 3 * NV * 2;       // f16, both batches
    const size_t tail   = (size_t)768 * sizeof(double) + 64;

    const int nb = (ws_size >= 2 * xbufB1 + probsB + tail) ? 2 : 1;

    unsigned char* xbuf  = (unsigned char*)ws;
    __half2*       probs = (__half2*)(ws + (size_t)nb * xbufB1);
    double*     partials = (double*)((char*)probs + probsB);
    int*           flags = (int*)((char*)partials + 768 * sizeof(double));

    hipMemsetAsync(flags, 0, 8 * sizeof(int), stream);

    for (int b0 = 0; b0 < 2; b0 += nb) {
        hipLaunchKernelGGL(k_scan_prob, dim3(SCANB + PROBB, nb), dim3(384), 0,
                           stream, gt, net, xbuf, probs, flags, b0);
        hipLaunchKernelGGL(k_yz_acc, dim3(XD, 3 * nb), dim3(768), 0, stream,
                           xbuf, probs, flags, partials, b0);
    }
    hipLaunchKernelGGL(k_reduce, dim3(1), dim3(256), 0, stream, partials,
                       768, out);
}